// Round 1
// baseline (1496.362 us; speedup 1.0000x reference)
//
#include <hip/hip_runtime.h>
#include <hip/hip_bf16.h>
#include <math.h>

#define BSZ 4
#define SEQ 1024
#define DIM 768
#define NH 12
#define NEnt 42
#define MM 8
#define PPairs 500
#define INC 3
#define OUTC 256
#define EMB 768
#define BLKsz 64
#define NG 12
#define NL 97
#define NPAIR (BSZ*PPairs)   // 2000

// Load a float input that may be stored as f32 or bf16 (runtime flag).
__device__ __forceinline__ float ldin(const void* p, long long i, int f32) {
  if (f32) return ((const float*)p)[i];
  unsigned int u = (unsigned int)(((const unsigned short*)p)[i]) << 16;
  union { unsigned int u; float f; } c; c.u = u;
  return c.f;
}

// Detect whether float inputs are f32 or bf16.
// For true f32 data, low-16 bits are random mantissa bits -> decoded as bf16,
// |v|>1 with p~0.5. For bf16 data, low-16 bits are real elements of W_head
// (scale 0.02) -> |v| << 1 always.
__global__ void k_detect(const void* w_head, int* flag) {
  int tid = threadIdx.x;  // 64
  unsigned int word = ((const unsigned int*)w_head)[tid];
  union { unsigned int u; float f; } c;
  c.u = (word & 0xFFFFu) << 16;
  float v = fabsf(c.f);
  unsigned long long m = __ballot(v > 1.0f);
  if (tid == 0) flag[0] = (__popcll(m) >= 8) ? 1 : 0;
}

// e_emb[b,e,d] = logsumexp over valid mentions of seq_out[b, idx, d]; cnt gate.
__global__ void k_eemb(const void* seq, const int* etok, const void* emask,
                       const int* flag, float* e_emb) {
  int be = blockIdx.x;            // b*NEnt+e
  int b = be / NEnt;
  int tid = threadIdx.x;          // 256
  int f32 = *flag;
  __shared__ int sidx[MM];
  __shared__ float sval[MM];
  if (tid < MM) {
    int t = etok[be*MM + tid];
    int ip = t + 1;
    float v = ldin(emask, be*MM + tid, f32);
    sval[tid] = (ip < SEQ) ? v : 0.0f;
    int ic = ip < 0 ? 0 : (ip > SEQ-1 ? SEQ-1 : ip);
    sidx[tid] = ic;
  }
  __syncthreads();
  float cnt = 0.0f;
#pragma unroll
  for (int m = 0; m < MM; m++) cnt += sval[m];
  for (int d = tid; d < DIM; d += 256) {
    float x[MM];
#pragma unroll
    for (int m = 0; m < MM; m++)
      x[m] = ldin(seq, ((long long)(b*SEQ) + sidx[m])*DIM + d, f32);
    float mx = -1e30f;
#pragma unroll
    for (int m = 0; m < MM; m++) if (sval[m] > 0.0f && x[m] > mx) mx = x[m];
    float s = 0.0f;
#pragma unroll
    for (int m = 0; m < MM; m++) if (sval[m] > 0.0f) s += expf(x[m] - mx);
    float e = (cnt > 0.0f) ? (mx + logf(s)) : 0.0f;
    e_emb[(long long)be*DIM + d] = e;
  }
}

// e_att[b,e,h,s] = mean over valid mentions of attention[b,h,idx,s]
__global__ void k_eatt(const void* att, const int* etok, const void* emask,
                       const int* flag, float* e_att) {
  int beh = blockIdx.x;            // (b*NEnt+e)*NH + h
  int h = beh % NH;
  int be = beh / NH;
  int b = be / NEnt;
  int tid = threadIdx.x;           // 256
  int f32 = *flag;
  __shared__ int sidx[MM];
  __shared__ float sval[MM];
  if (tid < MM) {
    int t = etok[be*MM + tid];
    int ip = t + 1;
    float v = ldin(emask, be*MM + tid, f32);
    sval[tid] = (ip < SEQ) ? v : 0.0f;
    int ic = ip < 0 ? 0 : (ip > SEQ-1 ? SEQ-1 : ip);
    sidx[tid] = ic;
  }
  __syncthreads();
  float cnt = 0.0f;
#pragma unroll
  for (int m = 0; m < MM; m++) cnt += sval[m];
  float rs = (cnt > 0.0f) ? 1.0f/fmaxf(cnt, 1.0f) : 0.0f;
  long long abase = ((long long)(b*NH + h))*SEQ*SEQ;
  for (int s = tid; s < SEQ; s += 256) {
    float acc = 0.0f;
#pragma unroll
    for (int m = 0; m < MM; m++)
      if (sval[m] > 0.0f)
        acc += sval[m]*ldin(att, abase + (long long)sidx[m]*SEQ + s, f32);
    e_att[((long long)be*NH + h)*SEQ + s] = acc*rs;
  }
}

// sp[b,s,c] = seq_out[b,s,:] @ W_liner[:,c]   (c=0..2)
__global__ void k_sp(const void* seq, const void* wliner, const int* flag,
                     float* sp) {
  int bs = blockIdx.x;            // b*SEQ + s, 4096 blocks
  int tid = threadIdx.x;          // 256
  int f32 = *flag;
  float a0 = 0, a1 = 0, a2 = 0;
  for (int d = tid; d < DIM; d += 256) {
    float x = ldin(seq, (long long)bs*DIM + d, f32);
    a0 += x*ldin(wliner, (long long)d*3 + 0, f32);
    a1 += x*ldin(wliner, (long long)d*3 + 1, f32);
    a2 += x*ldin(wliner, (long long)d*3 + 2, f32);
  }
  __shared__ float r0[256], r1[256], r2[256];
  r0[tid] = a0; r1[tid] = a1; r2[tid] = a2;
  __syncthreads();
  for (int o = 128; o > 0; o >>= 1) {
    if (tid < o) { r0[tid] += r0[tid+o]; r1[tid] += r1[tid+o]; r2[tid] += r2[tid+o]; }
    __syncthreads();
  }
  if (tid == 0) {
    sp[bs*3 + 0] = r0[0]; sp[bs*3 + 1] = r1[0]; sp[bs*3 + 2] = r2[0];
  }
}

// Per pair p: q[s] = (1/H) sum_h e_att[b,hi,h,s]*e_att[b,ti,h,s]
// v3[c] = (sum_s q*sp[b,s,c])/(sum_s q + 1e-5) + b_liner[c]
// h_t[p,o] = v3 @ W_seg[:,o] + b_seg[o]
__global__ void k_pair(const float* e_att, const float* sp, const int* hts,
                       const void* bliner, const void* wseg, const void* bseg,
                       const int* flag, float* h_t) {
  int p = blockIdx.x;             // 0..1999
  int b = p / PPairs;
  int tid = threadIdx.x;          // 256
  int f32 = *flag;
  int hi = hts[p*2 + 0];
  int ti = hts[p*2 + 1];
  const float* ei = e_att + ((long long)(b*NEnt + hi))*NH*SEQ;
  const float* ej = e_att + ((long long)(b*NEnt + ti))*NH*SEQ;
  float dn = 0, a0 = 0, a1 = 0, a2 = 0;
  for (int s = tid; s < SEQ; s += 256) {
    float q = 0.0f;
#pragma unroll
    for (int h = 0; h < NH; h++) q += ei[h*SEQ + s]*ej[h*SEQ + s];
    q *= (1.0f/NH);
    dn += q;
    a0 += q*sp[(b*SEQ + s)*3 + 0];
    a1 += q*sp[(b*SEQ + s)*3 + 1];
    a2 += q*sp[(b*SEQ + s)*3 + 2];
  }
  __shared__ float red[4][256];
  red[0][tid] = dn; red[1][tid] = a0; red[2][tid] = a1; red[3][tid] = a2;
  __syncthreads();
  for (int o = 128; o > 0; o >>= 1) {
    if (tid < o) {
      red[0][tid] += red[0][tid+o];
      red[1][tid] += red[1][tid+o];
      red[2][tid] += red[2][tid+o];
      red[3][tid] += red[3][tid+o];
    }
    __syncthreads();
  }
  float scale = 1.0f/(red[0][0] + 1e-5f);
  float v0 = red[1][0]*scale + ldin(bliner, 0, f32);
  float v1 = red[2][0]*scale + ldin(bliner, 1, f32);
  float v2 = red[3][0]*scale + ldin(bliner, 2, f32);
  float o = ldin(bseg, tid, f32)
          + v0*ldin(wseg, 0*OUTC + tid, f32)
          + v1*ldin(wseg, 1*OUTC + tid, f32)
          + v2*ldin(wseg, 2*OUTC + tid, f32);
  h_t[(long long)p*OUTC + tid] = o;
}

// hs/ts rows: tanh(concat(e_emb[b,ent], h_t[p]) @ W + b). 8 rows/block, y picks head/tail.
__global__ void k_headtail(const float* e_emb, const float* h_t, const int* hts,
                           const void* w_head, const void* b_head,
                           const void* w_tail, const void* b_tail,
                           const int* flag, float* hs, float* ts) {
  int xb = blockIdx.x;             // 0..249
  int y  = blockIdx.y;             // 0=head, 1=tail
  int tid = threadIdx.x;           // 256
  int f32 = *flag;
  const void* W  = y ? w_tail : w_head;
  const void* Bv = y ? b_tail : b_head;
  float* out = y ? ts : hs;
  __shared__ float rb[8][1024];    // 32 KB
  for (int r = 0; r < 8; r++) {
    int p = xb*8 + r;
    int b = p / PPairs;
    int ent = hts[p*2 + y];
    const float* er = e_emb + (long long)(b*NEnt + ent)*DIM;
    for (int k = tid; k < 1024; k += 256)
      rb[r][k] = (k < DIM) ? er[k] : h_t[(long long)p*OUTC + (k - DIM)];
  }
  __syncthreads();
  float acc[3][8];
#pragma unroll
  for (int j = 0; j < 3; j++)
#pragma unroll
    for (int r = 0; r < 8; r++) acc[j][r] = 0.0f;
  for (int k = 0; k < 1024; k++) {
    float rv[8];
#pragma unroll
    for (int r = 0; r < 8; r++) rv[r] = rb[r][k];
#pragma unroll
    for (int j = 0; j < 3; j++) {
      float w = ldin(W, (long long)k*EMB + tid + 256*j, f32);
#pragma unroll
      for (int r = 0; r < 8; r++) acc[j][r] += rv[r]*w;
    }
  }
#pragma unroll
  for (int j = 0; j < 3; j++) {
    int o = tid + 256*j;
    float bias = ldin(Bv, o, f32);
#pragma unroll
    for (int r = 0; r < 8; r++)
      out[(long long)(xb*8 + r)*EMB + o] = tanhf(acc[j][r] + bias);
  }
}

// Bilinear classifier partials: part[g][n][l] = sum_{a,b} hs[n,g,a]*ts[n,g,b]*W_bil[(g,a,b),l]
__global__ void k_bil(const float* hs, const float* ts, const void* w_bil,
                      const int* flag, float* part) {
  int x = blockIdx.x;              // 0..124 (16 rows each)
  int g = blockIdx.y;              // 0..11
  int tid = threadIdx.x;           // 128
  int f32 = *flag;
  __shared__ float hsg[16][BLKsz];
  __shared__ float tsg[16][BLKsz];
  __shared__ float prod[16][BLKsz];
  for (int i = tid; i < 16*BLKsz; i += 128) {
    int r = i >> 6, c = i & 63;
    hsg[r][c] = hs[(long long)(x*16 + r)*EMB + g*BLKsz + c];
    tsg[r][c] = ts[(long long)(x*16 + r)*EMB + g*BLKsz + c];
  }
  __syncthreads();
  float acc[16];
#pragma unroll
  for (int r = 0; r < 16; r++) acc[r] = 0.0f;
  int l = tid;
  for (int a = 0; a < 64; a++) {
    // cooperative staging of prod[r][b] = hs[r,g,a]*ts[r,g,b]
    for (int i = tid; i < 16*BLKsz; i += 128) {
      int r = i >> 6, bb = i & 63;
      prod[r][bb] = hsg[r][a]*tsg[r][bb];
    }
    __syncthreads();
    if (l < NL) {
      long long wb = ((long long)(g*4096 + a*64))*NL + l;
      for (int bb = 0; bb < 64; bb += 4) {
        float w0 = ldin(w_bil, wb + (long long)(bb+0)*NL, f32);
        float w1 = ldin(w_bil, wb + (long long)(bb+1)*NL, f32);
        float w2 = ldin(w_bil, wb + (long long)(bb+2)*NL, f32);
        float w3 = ldin(w_bil, wb + (long long)(bb+3)*NL, f32);
#pragma unroll
        for (int r = 0; r < 16; r++) {
          const float4 pv = *(const float4*)&prod[r][bb];
          acc[r] += pv.x*w0 + pv.y*w1 + pv.z*w2 + pv.w*w3;
        }
      }
    }
    __syncthreads();
  }
  if (l < NL) {
#pragma unroll
    for (int r = 0; r < 16; r++)
      part[((long long)g*NPAIR + x*16 + r)*NL + l] = acc[r];
  }
}

// logits = sum_g part + b_bil; store in output dtype.
__global__ void k_final(const float* part, const void* b_bil, const int* flag,
                        void* out) {
  int i = blockIdx.x*256 + threadIdx.x;
  if (i >= NPAIR*NL) return;
  int l = i % NL;
  int f32 = *flag;
  float v = ldin(b_bil, l, f32);
#pragma unroll
  for (int g = 0; g < NG; g++) v += part[(long long)g*NPAIR*NL + i];
  if (f32) ((float*)out)[i] = v;
  else ((__hip_bfloat16*)out)[i] = __float2bfloat16(v);
}

extern "C" void kernel_launch(void* const* d_in, const int* in_sizes, int n_in,
                              void* d_out, int out_size, void* d_ws, size_t ws_size,
                              hipStream_t stream) {
  const void* seq    = d_in[0];
  const void* att    = d_in[1];
  const int*  etok   = (const int*)d_in[2];
  const void* emask  = d_in[3];
  const int*  hts    = (const int*)d_in[4];
  const void* wliner = d_in[5];
  const void* bliner = d_in[6];
  const void* wseg   = d_in[7];
  const void* bseg   = d_in[8];
  const void* whead  = d_in[9];
  const void* bhead  = d_in[10];
  const void* wtail  = d_in[11];
  const void* btail  = d_in[12];
  const void* wbil   = d_in[13];
  const void* bbil   = d_in[14];

  char* ws = (char*)d_ws;
  int*   flag  = (int*)ws;                          // 1 KB pad
  float* e_emb = (float*)(ws + 1024);               // 129024 f
  float* e_att = e_emb + (long long)BSZ*NEnt*DIM;   // 2064384 f
  float* sp    = e_att + (long long)BSZ*NEnt*NH*SEQ;// 12288 f
  float* h_t   = sp    + (long long)BSZ*SEQ*INC;    // 512000 f
  float* hs    = h_t   + (long long)NPAIR*OUTC;     // 1536000 f
  float* ts    = hs    + (long long)NPAIR*EMB;      // 1536000 f
  float* part  = ts    + (long long)NPAIR*EMB;      // 2328000 f
  // total ~32.5 MB

  k_detect<<<1, 64, 0, stream>>>(whead, flag);
  k_eemb<<<BSZ*NEnt, 256, 0, stream>>>(seq, etok, emask, flag, e_emb);
  k_eatt<<<BSZ*NEnt*NH, 256, 0, stream>>>(att, etok, emask, flag, e_att);
  k_sp<<<BSZ*SEQ, 256, 0, stream>>>(seq, wliner, flag, sp);
  k_pair<<<NPAIR, 256, 0, stream>>>(e_att, sp, hts, bliner, wseg, bseg, flag, h_t);
  k_headtail<<<dim3(NPAIR/8, 2), 256, 0, stream>>>(e_emb, h_t, hts, whead, bhead,
                                                   wtail, btail, flag, hs, ts);
  k_bil<<<dim3(NPAIR/16, NG), 128, 0, stream>>>(hs, ts, wbil, flag, part);
  k_final<<<(NPAIR*NL + 255)/256, 256, 0, stream>>>(part, bbil, flag, d_out);
}

// Round 2
// 847.606 us; speedup vs baseline: 1.7654x; 1.7654x over previous
//
#include <hip/hip_runtime.h>
#include <hip/hip_bf16.h>
#include <math.h>

#define BSZ 4
#define SEQ 1024
#define DIM 768
#define NH 12
#define NEnt 42
#define MM 8
#define PPairs 500
#define INC 3
#define OUTC 256
#define EMB 768
#define BLKsz 64
#define NG 12
#define NL 97
#define NPAIR (BSZ*PPairs)   // 2000
#define NGC 6                // g-chunks for k_bilmfma (2 groups each)

typedef __bf16 bf16x8 __attribute__((ext_vector_type(8)));
typedef float f32x4 __attribute__((ext_vector_type(4)));

// Load a float input that may be stored as f32 or bf16 (runtime flag).
__device__ __forceinline__ float ldin(const void* p, long long i, int f32) {
  if (f32) return ((const float*)p)[i];
  unsigned int u = (unsigned int)(((const unsigned short*)p)[i]) << 16;
  union { unsigned int u; float f; } c; c.u = u;
  return c.f;
}

// Detect whether float inputs are f32 or bf16 (see R0 notes).
__global__ void k_detect(const void* w_head, int* flag) {
  int tid = threadIdx.x;  // 64
  unsigned int word = ((const unsigned int*)w_head)[tid];
  union { unsigned int u; float f; } c;
  c.u = (word & 0xFFFFu) << 16;
  float v = fabsf(c.f);
  unsigned long long m = __ballot(v > 1.0f);
  if (tid == 0) flag[0] = (__popcll(m) >= 8) ? 1 : 0;
}

// One-time: W_bil[(g*4096+k)*97+l] -> wT[(g*97+l)*4096+k] as bf16.
__global__ void k_wT(const void* wbil, const int* flag, __bf16* wT) {
  __shared__ float t[128][98];
  int kb = blockIdx.x, g = blockIdx.y, tid = threadIdx.x;  // 32 x 12, 256 thr
  int f32 = *flag;
  long long base = ((long long)g*4096 + kb*128)*97;
  for (int i = tid; i < 128*97; i += 256)
    t[i/97][i%97] = ldin(wbil, base + i, f32);
  __syncthreads();
  for (int j = tid; j < 97*128; j += 256) {
    int l = j >> 7, k = j & 127;
    wT[((long long)g*97 + l)*4096 + kb*128 + k] = (__bf16)t[k][l];
  }
}

// e_emb[b,e,d] = logsumexp over valid mentions of seq_out[b, idx, d].
__global__ void k_eemb(const void* seq, const int* etok, const void* emask,
                       const int* flag, float* e_emb) {
  int be = blockIdx.x;
  int b = be / NEnt;
  int tid = threadIdx.x;          // 256
  int f32 = *flag;
  __shared__ int sidx[MM];
  __shared__ float sval[MM];
  if (tid < MM) {
    int t = etok[be*MM + tid];
    int ip = t + 1;
    float v = ldin(emask, be*MM + tid, f32);
    sval[tid] = (ip < SEQ) ? v : 0.0f;
    int ic = ip < 0 ? 0 : (ip > SEQ-1 ? SEQ-1 : ip);
    sidx[tid] = ic;
  }
  __syncthreads();
  float cnt = 0.0f;
#pragma unroll
  for (int m = 0; m < MM; m++) cnt += sval[m];
  for (int d = tid; d < DIM; d += 256) {
    float x[MM];
#pragma unroll
    for (int m = 0; m < MM; m++)
      x[m] = ldin(seq, ((long long)(b*SEQ) + sidx[m])*DIM + d, f32);
    float mx = -1e30f;
#pragma unroll
    for (int m = 0; m < MM; m++) if (sval[m] > 0.0f && x[m] > mx) mx = x[m];
    float s = 0.0f;
#pragma unroll
    for (int m = 0; m < MM; m++) if (sval[m] > 0.0f) s += expf(x[m] - mx);
    float e = (cnt > 0.0f) ? (mx + logf(s)) : 0.0f;
    e_emb[(long long)be*DIM + d] = e;
  }
}

// e_att[b,e,h,s] = mean over valid mentions of attention[b,h,idx,s]
__global__ void k_eatt(const void* att, const int* etok, const void* emask,
                       const int* flag, float* e_att) {
  int beh = blockIdx.x;
  int h = beh % NH;
  int be = beh / NH;
  int b = be / NEnt;
  int tid = threadIdx.x;           // 256
  int f32 = *flag;
  __shared__ int sidx[MM];
  __shared__ float sval[MM];
  if (tid < MM) {
    int t = etok[be*MM + tid];
    int ip = t + 1;
    float v = ldin(emask, be*MM + tid, f32);
    sval[tid] = (ip < SEQ) ? v : 0.0f;
    int ic = ip < 0 ? 0 : (ip > SEQ-1 ? SEQ-1 : ip);
    sidx[tid] = ic;
  }
  __syncthreads();
  float cnt = 0.0f;
#pragma unroll
  for (int m = 0; m < MM; m++) cnt += sval[m];
  float rs = (cnt > 0.0f) ? 1.0f/fmaxf(cnt, 1.0f) : 0.0f;
  long long abase = ((long long)(b*NH + h))*SEQ*SEQ;
  for (int s = tid; s < SEQ; s += 256) {
    float acc = 0.0f;
#pragma unroll
    for (int m = 0; m < MM; m++)
      if (sval[m] > 0.0f)
        acc += sval[m]*ldin(att, abase + (long long)sidx[m]*SEQ + s, f32);
    e_att[((long long)be*NH + h)*SEQ + s] = acc*rs;
  }
}

// sp[b,s,c] = seq_out[b,s,:] @ W_liner[:,c]
__global__ void k_sp(const void* seq, const void* wliner, const int* flag,
                     float* sp) {
  int bs = blockIdx.x;
  int tid = threadIdx.x;          // 256
  int f32 = *flag;
  float a0 = 0, a1 = 0, a2 = 0;
  for (int d = tid; d < DIM; d += 256) {
    float x = ldin(seq, (long long)bs*DIM + d, f32);
    a0 += x*ldin(wliner, (long long)d*3 + 0, f32);
    a1 += x*ldin(wliner, (long long)d*3 + 1, f32);
    a2 += x*ldin(wliner, (long long)d*3 + 2, f32);
  }
  __shared__ float r0[256], r1[256], r2[256];
  r0[tid] = a0; r1[tid] = a1; r2[tid] = a2;
  __syncthreads();
  for (int o = 128; o > 0; o >>= 1) {
    if (tid < o) { r0[tid] += r0[tid+o]; r1[tid] += r1[tid+o]; r2[tid] += r2[tid+o]; }
    __syncthreads();
  }
  if (tid == 0) {
    sp[bs*3 + 0] = r0[0]; sp[bs*3 + 1] = r1[0]; sp[bs*3 + 2] = r2[0];
  }
}

// Per-pair weighted pooling + seg projection -> h_t[p][256]
__global__ void k_pair(const float* e_att, const float* sp, const int* hts,
                       const void* bliner, const void* wseg, const void* bseg,
                       const int* flag, float* h_t) {
  int p = blockIdx.x;
  int b = p / PPairs;
  int tid = threadIdx.x;          // 256
  int f32 = *flag;
  int hi = hts[p*2 + 0];
  int ti = hts[p*2 + 1];
  const float* ei = e_att + ((long long)(b*NEnt + hi))*NH*SEQ;
  const float* ej = e_att + ((long long)(b*NEnt + ti))*NH*SEQ;
  float dn = 0, a0 = 0, a1 = 0, a2 = 0;
  for (int s = tid; s < SEQ; s += 256) {
    float q = 0.0f;
#pragma unroll
    for (int h = 0; h < NH; h++) q += ei[h*SEQ + s]*ej[h*SEQ + s];
    q *= (1.0f/NH);
    dn += q;
    a0 += q*sp[(b*SEQ + s)*3 + 0];
    a1 += q*sp[(b*SEQ + s)*3 + 1];
    a2 += q*sp[(b*SEQ + s)*3 + 2];
  }
  __shared__ float red[4][256];
  red[0][tid] = dn; red[1][tid] = a0; red[2][tid] = a1; red[3][tid] = a2;
  __syncthreads();
  for (int o = 128; o > 0; o >>= 1) {
    if (tid < o) {
      red[0][tid] += red[0][tid+o];
      red[1][tid] += red[1][tid+o];
      red[2][tid] += red[2][tid+o];
      red[3][tid] += red[3][tid+o];
    }
    __syncthreads();
  }
  float scale = 1.0f/(red[0][0] + 1e-5f);
  float v0 = red[1][0]*scale + ldin(bliner, 0, f32);
  float v1 = red[2][0]*scale + ldin(bliner, 1, f32);
  float v2 = red[3][0]*scale + ldin(bliner, 2, f32);
  float o = ldin(bseg, tid, f32)
          + v0*ldin(wseg, 0*OUTC + tid, f32)
          + v1*ldin(wseg, 1*OUTC + tid, f32)
          + v2*ldin(wseg, 2*OUTC + tid, f32);
  h_t[(long long)p*OUTC + tid] = o;
}

// hs/ts rows: tanh(concat(e_emb, h_t) @ W + b), output bf16.
__global__ void k_headtail(const float* e_emb, const float* h_t, const int* hts,
                           const void* w_head, const void* b_head,
                           const void* w_tail, const void* b_tail,
                           const int* flag, __bf16* hs, __bf16* ts) {
  int xb = blockIdx.x;             // 0..249
  int y  = blockIdx.y;             // 0=head, 1=tail
  int tid = threadIdx.x;           // 256
  int f32 = *flag;
  const void* W  = y ? w_tail : w_head;
  const void* Bv = y ? b_tail : b_head;
  __bf16* out = y ? ts : hs;
  __shared__ float rb[8][1024];    // 32 KB
  for (int r = 0; r < 8; r++) {
    int p = xb*8 + r;
    int b = p / PPairs;
    int ent = hts[p*2 + y];
    const float* er = e_emb + (long long)(b*NEnt + ent)*DIM;
    for (int k = tid; k < 1024; k += 256)
      rb[r][k] = (k < DIM) ? er[k] : h_t[(long long)p*OUTC + (k - DIM)];
  }
  __syncthreads();
  float acc[3][8];
#pragma unroll
  for (int j = 0; j < 3; j++)
#pragma unroll
    for (int r = 0; r < 8; r++) acc[j][r] = 0.0f;
  for (int k = 0; k < 1024; k++) {
    float rv[8];
#pragma unroll
    for (int r = 0; r < 8; r++) rv[r] = rb[r][k];
#pragma unroll
    for (int j = 0; j < 3; j++) {
      float w = ldin(W, (long long)k*EMB + tid + 256*j, f32);
#pragma unroll
      for (int r = 0; r < 8; r++) acc[j][r] += rv[r]*w;
    }
  }
#pragma unroll
  for (int j = 0; j < 3; j++) {
    int o = tid + 256*j;
    float bias = ldin(Bv, o, f32);
#pragma unroll
    for (int r = 0; r < 8; r++)
      out[(long long)(xb*8 + r)*EMB + o] = (__bf16)tanhf(acc[j][r] + bias);
  }
}

// MFMA bilinear: part[gc][n][l] = sum over g in chunk, (a,b):
//   hs[n,g,a]*ts[n,g,b]*W_bil[(g,a,b),l]
// Wave owns 32 rows x 112 cols. A-frag built on the fly: scalar hs * ts-vec.
// B-frags load straight from pre-transposed wT (no barriers in K-loop).
__global__ void k_bilmfma(const __bf16* hsb, const __bf16* tsb,
                          const __bf16* wT, float* part) {
  __shared__ __bf16 hsl[128][72];   // pitch 72: b128-aligned rows, 2-way banks
  __shared__ __bf16 tsl[128][72];
  int tid = threadIdx.x;            // 256 = 4 waves
  int row0 = blockIdx.x * 128;      // 16 M-blocks
  int gc = blockIdx.y;              // 0..5, two groups each
  int wid = tid >> 6;
  int lane = tid & 63;
  int quad = lane >> 4;
  int col = lane & 15;

  f32x4 acc[2][7];
#pragma unroll
  for (int mf = 0; mf < 2; mf++)
#pragma unroll
    for (int nt = 0; nt < 7; nt++) acc[mf][nt] = (f32x4){0,0,0,0};

  for (int gg = 0; gg < 2; gg++) {
    int g = gc*2 + gg;
    __syncthreads();   // protect LDS from previous iteration's readers
    // stage hs/ts row-slices for this g (128 rows x 64 bf16 each)
    for (int c = tid; c < 128*8; c += 256) {
      int r = c >> 3, off = (c & 7)*8;
      int gr = row0 + r;
      bf16x8 hv = {}, tv = {};
      if (gr < NPAIR) {
        hv = *(const bf16x8*)(hsb + (long long)gr*EMB + g*BLKsz + off);
        tv = *(const bf16x8*)(tsb + (long long)gr*EMB + g*BLKsz + off);
      }
      *(bf16x8*)&hsl[r][off] = hv;
      *(bf16x8*)&tsl[r][off] = tv;
    }
    __syncthreads();

    const __bf16* wg = wT + (long long)g*NL*4096;
    for (int kk = 0; kk < 4096; kk += 32) {
      int a = kk >> 6;
      int b0 = kk & 63;
      // B fragments: [l][k] k-consecutive, straight from global
      bf16x8 bv[7];
#pragma unroll
      for (int nt = 0; nt < 7; nt++) {
        int l = nt*16 + col;
        bf16x8 z = {};
        bv[nt] = (l < NL) ? *(const bf16x8*)(wg + (long long)l*4096 + kk + quad*8)
                          : z;
      }
      // A fragments: bl[m][k] = hs[m][a] * ts[m][b0 + klocal]
      bf16x8 af[2];
#pragma unroll
      for (int mf = 0; mf < 2; mf++) {
        int r = wid*32 + mf*16 + col;
        float hv = (float)hsl[r][a];
        bf16x8 tv = *(bf16x8*)&tsl[r][b0 + quad*8];
#pragma unroll
        for (int j = 0; j < 8; j++) af[mf][j] = (__bf16)((float)tv[j] * hv);
      }
#pragma unroll
      for (int nt = 0; nt < 7; nt++)
#pragma unroll
        for (int mf = 0; mf < 2; mf++)
          acc[mf][nt] = __builtin_amdgcn_mfma_f32_16x16x32_bf16(
              af[mf], bv[nt], acc[mf][nt], 0, 0, 0);
    }
  }
  // D layout: col=lane&15, row=quad*4+reg
#pragma unroll
  for (int mf = 0; mf < 2; mf++)
#pragma unroll
    for (int nt = 0; nt < 7; nt++)
#pragma unroll
      for (int reg = 0; reg < 4; reg++) {
        int n = row0 + wid*32 + mf*16 + quad*4 + reg;
        int l = nt*16 + col;
        if (n < NPAIR && l < NL)
          part[((long long)gc*NPAIR + n)*NL + l] = acc[mf][nt][reg];
      }
}

// logits = sum_gc part + b_bil; store in output dtype.
__global__ void k_final(const float* part, const void* b_bil, const int* flag,
                        void* out) {
  int i = blockIdx.x*256 + threadIdx.x;
  if (i >= NPAIR*NL) return;
  int l = i % NL;
  int f32 = *flag;
  float v = ldin(b_bil, l, f32);
#pragma unroll
  for (int g = 0; g < NGC; g++) v += part[(long long)g*NPAIR*NL + i];
  if (f32) ((float*)out)[i] = v;
  else ((__hip_bfloat16*)out)[i] = __float2bfloat16(v);
}

extern "C" void kernel_launch(void* const* d_in, const int* in_sizes, int n_in,
                              void* d_out, int out_size, void* d_ws, size_t ws_size,
                              hipStream_t stream) {
  const void* seq    = d_in[0];
  const void* att    = d_in[1];
  const int*  etok   = (const int*)d_in[2];
  const void* emask  = d_in[3];
  const int*  hts    = (const int*)d_in[4];
  const void* wliner = d_in[5];
  const void* bliner = d_in[6];
  const void* wseg   = d_in[7];
  const void* bseg   = d_in[8];
  const void* whead  = d_in[9];
  const void* bhead  = d_in[10];
  const void* wtail  = d_in[11];
  const void* btail  = d_in[12];
  const void* wbil   = d_in[13];
  const void* bbil   = d_in[14];

  char* ws = (char*)d_ws;
  int*    flag  = (int*)ws;                              // @0, 1 KB
  float*  e_emb = (float*)(ws + 1024);                   // 516096 B
  float*  e_att = e_emb + (long long)BSZ*NEnt*DIM;       // 8257536 B
  float*  sp    = e_att + (long long)BSZ*NEnt*NH*SEQ;    // 49152 B
  float*  h_t   = sp    + (long long)BSZ*SEQ*INC;        // 2048000 B
  __bf16* hsb   = (__bf16*)(h_t + (long long)NPAIR*OUTC);// 3072000 B
  __bf16* tsb   = hsb + (long long)NPAIR*EMB;            // 3072000 B
  float*  part  = (float*)(tsb + (long long)NPAIR*EMB);  // 4656000 B
  __bf16* wT    = (__bf16*)(part + (long long)NGC*NPAIR*NL); // 9535488 B
  // total ~29.8 MiB

  k_detect<<<1, 64, 0, stream>>>(whead, flag);
  k_wT<<<dim3(32, 12), 256, 0, stream>>>(wbil, flag, wT);
  k_eemb<<<BSZ*NEnt, 256, 0, stream>>>(seq, etok, emask, flag, e_emb);
  k_eatt<<<BSZ*NEnt*NH, 256, 0, stream>>>(att, etok, emask, flag, e_att);
  k_sp<<<BSZ*SEQ, 256, 0, stream>>>(seq, wliner, flag, sp);
  k_pair<<<NPAIR, 256, 0, stream>>>(e_att, sp, hts, bliner, wseg, bseg, flag, h_t);
  k_headtail<<<dim3(NPAIR/8, 2), 256, 0, stream>>>(e_emb, h_t, hts, whead, bhead,
                                                   wtail, btail, flag, hsb, tsb);
  k_bilmfma<<<dim3(16, NGC), 256, 0, stream>>>(hsb, tsb, wT, part);
  k_final<<<(NPAIR*NL + 255)/256, 256, 0, stream>>>(part, bbil, flag, d_out);
}

// Round 3
// 674.486 us; speedup vs baseline: 2.2185x; 1.2567x over previous
//
#include <hip/hip_runtime.h>
#include <hip/hip_bf16.h>
#include <math.h>

#define BSZ 4
#define SEQ 1024
#define DIM 768
#define NH 12
#define NEnt 42
#define MM 8
#define PPairs 500
#define INC 3
#define OUTC 256
#define EMB 768
#define BLKsz 64
#define NG 12
#define NL 97
#define NPAIR (BSZ*PPairs)   // 2000
#define XROWS 2048           // padded rows for X / MFMA tiles

typedef __bf16 bf16x8 __attribute__((ext_vector_type(8)));
typedef float f32x4 __attribute__((ext_vector_type(4)));

// ---- workspace byte offsets (lifetime-aliased; peak ~26.2 MB) ----
// flag   @0        (4096)
// e_emb  @4096     516096   f32 [4*42*768]        dead after k_buildx
// e_att  @520192   8257536  f32 [4*42*12*1024]    dead after k_pair
// sp     @8777728  49152    f32 [4096*3]          dead after k_pair
// h_t    @8826880  2048000  f32 [2000*256]        dead after k_buildx
// Xb     @10874880 8388608  bf16 [2*2048*1024]    dead after k_htmm
// hsb    @19263488 3072000  bf16 [2000*768]
// tsb    @22335488 3072000  bf16 [2000*768]
// part   @25407488 776000   f32 [2000*97]
// whT    @4096     3145728  bf16 [2*768*1024]     (alias e_emb/e_att; written after k_buildx)
// wT     @8826880  9535488  bf16 [12*97*4096]     (alias h_t/Xb; written after k_htmm)
#define OFF_EEMB  4096
#define OFF_EATT  520192
#define OFF_SP    8777728
#define OFF_HT    8826880
#define OFF_XB    10874880
#define OFF_HSB   19263488
#define OFF_TSB   22335488
#define OFF_PART  25407488
#define OFF_WHT   4096
#define OFF_WT    8826880

// Load a float input that may be stored as f32 or bf16 (runtime flag).
__device__ __forceinline__ float ldin(const void* p, long long i, int f32) {
  if (f32) return ((const float*)p)[i];
  unsigned int u = (unsigned int)(((const unsigned short*)p)[i]) << 16;
  union { unsigned int u; float f; } c; c.u = u;
  return c.f;
}

__device__ __forceinline__ float tanhf_fast(float x) {
  float ax = fabsf(x);
  float t = __expf(-2.0f*ax);
  float r = (1.0f - t)/(1.0f + t);
  return x < 0.0f ? -r : r;
}

// Detect whether float inputs are f32 or bf16 (see R0 notes).
__global__ void k_detect(const void* w_head, int* flag) {
  int tid = threadIdx.x;  // 64
  unsigned int word = ((const unsigned int*)w_head)[tid];
  union { unsigned int u; float f; } c;
  c.u = (word & 0xFFFFu) << 16;
  float v = fabsf(c.f);
  unsigned long long m = __ballot(v > 1.0f);
  if (tid == 0) flag[0] = (__popcll(m) >= 8) ? 1 : 0;
}

// One-time: W_bil[(g*4096+k)*97+l] -> wT[(g*97+l)*4096+k] as bf16.
__global__ void k_wT(const void* wbil, const int* flag, __bf16* wT) {
  __shared__ float t[128][98];
  int kb = blockIdx.x, g = blockIdx.y, tid = threadIdx.x;  // 32 x 12, 256 thr
  int f32 = *flag;
  long long base = ((long long)g*4096 + kb*128)*97;
  for (int i = tid; i < 128*97; i += 256)
    t[i/97][i%97] = ldin(wbil, base + i, f32);
  __syncthreads();
  for (int j = tid; j < 97*128; j += 256) {
    int l = j >> 7, k = j & 127;
    wT[((long long)g*97 + l)*4096 + kb*128 + k] = (__bf16)t[k][l];
  }
}

// One-time: W_head/W_tail [1024][768] -> whT[y][768][1024] bf16.
__global__ void k_whT(const void* whead, const void* wtail, const int* flag,
                      __bf16* whT) {
  __shared__ float t[64][65];
  int kb = blockIdx.x, nb = blockIdx.y, y = blockIdx.z;  // 16 x 12 x 2
  int tid = threadIdx.x;  // 256
  int f32 = *flag;
  const void* W = y ? wtail : whead;
  for (int i = tid; i < 64*64; i += 256) {
    int r = i >> 6, c = i & 63;  // r = k-local, c = n-local
    t[r][c] = ldin(W, (long long)(kb*64 + r)*EMB + nb*64 + c, f32);
  }
  __syncthreads();
  for (int j = tid; j < 64*64; j += 256) {
    int r = j >> 6, k = j & 63;  // r = n-local, k = k-local
    whT[((long long)y*EMB + nb*64 + r)*1024 + kb*64 + k] = (__bf16)t[k][r];
  }
}

// e_emb[b,e,d] = logsumexp over valid mentions of seq_out[b, idx, d].
__global__ void k_eemb(const void* seq, const int* etok, const void* emask,
                       const int* flag, float* e_emb) {
  int be = blockIdx.x;
  int b = be / NEnt;
  int tid = threadIdx.x;          // 256
  int f32 = *flag;
  __shared__ int sidx[MM];
  __shared__ float sval[MM];
  if (tid < MM) {
    int t = etok[be*MM + tid];
    int ip = t + 1;
    float v = ldin(emask, be*MM + tid, f32);
    sval[tid] = (ip < SEQ) ? v : 0.0f;
    int ic = ip < 0 ? 0 : (ip > SEQ-1 ? SEQ-1 : ip);
    sidx[tid] = ic;
  }
  __syncthreads();
  float cnt = 0.0f;
#pragma unroll
  for (int m = 0; m < MM; m++) cnt += sval[m];
  for (int d = tid; d < DIM; d += 256) {
    float x[MM];
#pragma unroll
    for (int m = 0; m < MM; m++)
      x[m] = ldin(seq, ((long long)(b*SEQ) + sidx[m])*DIM + d, f32);
    float mx = -1e30f;
#pragma unroll
    for (int m = 0; m < MM; m++) if (sval[m] > 0.0f && x[m] > mx) mx = x[m];
    float s = 0.0f;
#pragma unroll
    for (int m = 0; m < MM; m++) if (sval[m] > 0.0f) s += expf(x[m] - mx);
    float e = (cnt > 0.0f) ? (mx + logf(s)) : 0.0f;
    e_emb[(long long)be*DIM + d] = e;
  }
}

// e_att[b,e,h,s] = mean over valid mentions of attention[b,h,idx,s]
__global__ void k_eatt(const void* att, const int* etok, const void* emask,
                       const int* flag, float* e_att) {
  int beh = blockIdx.x;
  int h = beh % NH;
  int be = beh / NH;
  int b = be / NEnt;
  int tid = threadIdx.x;           // 256
  int f32 = *flag;
  __shared__ int sidx[MM];
  __shared__ float sval[MM];
  if (tid < MM) {
    int t = etok[be*MM + tid];
    int ip = t + 1;
    float v = ldin(emask, be*MM + tid, f32);
    sval[tid] = (ip < SEQ) ? v : 0.0f;
    int ic = ip < 0 ? 0 : (ip > SEQ-1 ? SEQ-1 : ip);
    sidx[tid] = ic;
  }
  __syncthreads();
  float cnt = 0.0f;
#pragma unroll
  for (int m = 0; m < MM; m++) cnt += sval[m];
  float rs = (cnt > 0.0f) ? 1.0f/fmaxf(cnt, 1.0f) : 0.0f;
  long long abase = ((long long)(b*NH + h))*SEQ*SEQ;
  for (int s = tid; s < SEQ; s += 256) {
    float acc = 0.0f;
#pragma unroll
    for (int m = 0; m < MM; m++)
      if (sval[m] > 0.0f)
        acc += sval[m]*ldin(att, abase + (long long)sidx[m]*SEQ + s, f32);
    e_att[((long long)be*NH + h)*SEQ + s] = acc*rs;
  }
}

// sp[b,s,c] = seq_out[b,s,:] @ W_liner[:,c]
__global__ void k_sp(const void* seq, const void* wliner, const int* flag,
                     float* sp) {
  int bs = blockIdx.x;
  int tid = threadIdx.x;          // 256
  int f32 = *flag;
  float a0 = 0, a1 = 0, a2 = 0;
  for (int d = tid; d < DIM; d += 256) {
    float x = ldin(seq, (long long)bs*DIM + d, f32);
    a0 += x*ldin(wliner, (long long)d*3 + 0, f32);
    a1 += x*ldin(wliner, (long long)d*3 + 1, f32);
    a2 += x*ldin(wliner, (long long)d*3 + 2, f32);
  }
  __shared__ float r0[256], r1[256], r2[256];
  r0[tid] = a0; r1[tid] = a1; r2[tid] = a2;
  __syncthreads();
  for (int o = 128; o > 0; o >>= 1) {
    if (tid < o) { r0[tid] += r0[tid+o]; r1[tid] += r1[tid+o]; r2[tid] += r2[tid+o]; }
    __syncthreads();
  }
  if (tid == 0) {
    sp[bs*3 + 0] = r0[0]; sp[bs*3 + 1] = r1[0]; sp[bs*3 + 2] = r2[0];
  }
}

// Per-pair weighted pooling + seg projection -> h_t[p][256]
__global__ void k_pair(const float* e_att, const float* sp, const int* hts,
                       const void* bliner, const void* wseg, const void* bseg,
                       const int* flag, float* h_t) {
  int p = blockIdx.x;
  int b = p / PPairs;
  int tid = threadIdx.x;          // 256
  int f32 = *flag;
  int hi = hts[p*2 + 0];
  int ti = hts[p*2 + 1];
  const float* ei = e_att + ((long long)(b*NEnt + hi))*NH*SEQ;
  const float* ej = e_att + ((long long)(b*NEnt + ti))*NH*SEQ;
  float dn = 0, a0 = 0, a1 = 0, a2 = 0;
  for (int s = tid; s < SEQ; s += 256) {
    float q = 0.0f;
#pragma unroll
    for (int h = 0; h < NH; h++) q += ei[h*SEQ + s]*ej[h*SEQ + s];
    q *= (1.0f/NH);
    dn += q;
    a0 += q*sp[(b*SEQ + s)*3 + 0];
    a1 += q*sp[(b*SEQ + s)*3 + 1];
    a2 += q*sp[(b*SEQ + s)*3 + 2];
  }
  __shared__ float red[4][256];
  red[0][tid] = dn; red[1][tid] = a0; red[2][tid] = a1; red[3][tid] = a2;
  __syncthreads();
  for (int o = 128; o > 0; o >>= 1) {
    if (tid < o) {
      red[0][tid] += red[0][tid+o];
      red[1][tid] += red[1][tid+o];
      red[2][tid] += red[2][tid+o];
      red[3][tid] += red[3][tid+o];
    }
    __syncthreads();
  }
  float scale = 1.0f/(red[0][0] + 1e-5f);
  float v0 = red[1][0]*scale + ldin(bliner, 0, f32);
  float v1 = red[2][0]*scale + ldin(bliner, 1, f32);
  float v2 = red[3][0]*scale + ldin(bliner, 2, f32);
  float o = ldin(bseg, tid, f32)
          + v0*ldin(wseg, 0*OUTC + tid, f32)
          + v1*ldin(wseg, 1*OUTC + tid, f32)
          + v2*ldin(wseg, 2*OUTC + tid, f32);
  h_t[(long long)p*OUTC + tid] = o;
}

// Build X[y][p][k] = bf16(concat(e_emb[b, hts[p,y]], h_t[p])[k]); zero-pad rows.
__global__ void k_buildx(const float* e_emb, const float* h_t, const int* hts,
                         __bf16* Xb) {
  int p = blockIdx.x;              // 0..2047
  int y = blockIdx.y;
  int tid = threadIdx.x;           // 256
  __bf16* dst = Xb + ((long long)y*XROWS + p)*1024;
  if (p >= NPAIR) {
    for (int k = tid; k < 1024; k += 256) dst[k] = (__bf16)0.0f;
    return;
  }
  int b = p / PPairs;
  int ent = hts[p*2 + y];
  const float* er = e_emb + (long long)(b*NEnt + ent)*DIM;
  for (int k = tid; k < 1024; k += 256) {
    float v = (k < DIM) ? er[k] : h_t[(long long)p*OUTC + (k - DIM)];
    dst[k] = (__bf16)v;
  }
}

// MFMA head/tail projection: out = tanh(X @ W + b) as bf16 [2000][768].
// Barrier-free: A/B fragments straight from global (L1/L2 resident).
__global__ void k_htmm(const __bf16* Xb, const __bf16* whT,
                       const void* bhead, const void* btail, const int* flag,
                       __bf16* hsb, __bf16* tsb) {
  int tid = threadIdx.x;            // 256 = 4 waves
  int wid = tid >> 6, lane = tid & 63, quad = lane >> 4, col = lane & 15;
  int m0 = blockIdx.x*64 + wid*16;  // 32 m-blocks
  int n0 = blockIdx.y*128;          // 6 n-blocks
  int y  = blockIdx.z;
  int f32 = *flag;
  const __bf16* Xrow = Xb + ((long long)y*XROWS + m0 + col)*1024;
  f32x4 acc[8];
#pragma unroll
  for (int nt = 0; nt < 8; nt++) acc[nt] = (f32x4){0,0,0,0};
  for (int kk = 0; kk < 1024; kk += 32) {
    bf16x8 av = *(const bf16x8*)(Xrow + kk + quad*8);
#pragma unroll
    for (int nt = 0; nt < 8; nt++) {
      bf16x8 bv = *(const bf16x8*)(whT + ((long long)y*EMB + n0 + nt*16 + col)*1024
                                   + kk + quad*8);
      acc[nt] = __builtin_amdgcn_mfma_f32_16x16x32_bf16(av, bv, acc[nt], 0, 0, 0);
    }
  }
  const void* Bv = y ? btail : bhead;
  __bf16* out = y ? tsb : hsb;
#pragma unroll
  for (int nt = 0; nt < 8; nt++) {
    int n = n0 + nt*16 + col;
    float bias = ldin(Bv, n, f32);
#pragma unroll
    for (int reg = 0; reg < 4; reg++) {
      int m = m0 + quad*4 + reg;
      if (m < NPAIR)
        out[(long long)m*EMB + n] = (__bf16)tanhf_fast(acc[nt][reg] + bias);
    }
  }
}

// Zero part (re-poisoned to 0xAA each call).
__global__ void k_zero(float* part) {
  int i = blockIdx.x*256 + threadIdx.x;     // float4 index
  if (i < (NPAIR*NL)/4) ((f32x4*)part)[i] = (f32x4){0,0,0,0};
}

// MFMA bilinear: part[n][l] += sum_{a,b} hs[n,g,a]*ts[n,g,b]*W_bil[(g,a,b),l]
// Wave = 16 rows x 112 cols, one g per block. Grid (32,12) = 1536 waves.
// B-frags register-double-buffered from pre-transposed wT.
__global__ void k_bilmfma(const __bf16* hsb, const __bf16* tsb,
                          const __bf16* wT, float* part) {
  __shared__ __bf16 hslT[64][72];   // [a][row] transposed for conflict-free scalar read
  __shared__ __bf16 tsl[64][72];    // [row][b]
  int tid = threadIdx.x;            // 256 = 4 waves
  int m0 = blockIdx.x * 64;         // 32 m-blocks
  int g  = blockIdx.y;              // 0..11
  int wid = tid >> 6, lane = tid & 63, quad = lane >> 4, col = lane & 15;

  // stage hs/ts row-slices for this g (64 rows x 64 bf16 each)
  for (int i = tid; i < 64*8; i += 256) {
    int r = i >> 3, c0 = (i & 7)*8;
    int gr = m0 + r;
    bf16x8 hv = {}, tv = {};
    if (gr < NPAIR) {
      hv = *(const bf16x8*)(hsb + (long long)gr*EMB + g*BLKsz + c0);
      tv = *(const bf16x8*)(tsb + (long long)gr*EMB + g*BLKsz + c0);
    }
#pragma unroll
    for (int j = 0; j < 8; j++) hslT[c0+j][r] = hv[j];
    *(bf16x8*)&tsl[r][c0] = tv;
  }
  __syncthreads();

  int rloc = wid*16 + col;
  const __bf16* wg = wT + (long long)g*NL*4096;
  // per-nt clamped l (lanes with l>96 load row 96; results masked at store)
  long long boff[7];
#pragma unroll
  for (int nt = 0; nt < 7; nt++) {
    int l = nt*16 + col; if (l > 96) l = 96;
    boff[nt] = (long long)l*4096 + quad*8;
  }
  f32x4 acc[7];
#pragma unroll
  for (int nt = 0; nt < 7; nt++) acc[nt] = (f32x4){0,0,0,0};

  bf16x8 bv[7];
#pragma unroll
  for (int nt = 0; nt < 7; nt++) bv[nt] = *(const bf16x8*)(wg + boff[nt]);

  for (int kk = 0; kk < 4096; kk += 32) {
    int kn = (kk + 32 < 4096) ? kk + 32 : kk;
    bf16x8 bn[7];
#pragma unroll
    for (int nt = 0; nt < 7; nt++) bn[nt] = *(const bf16x8*)(wg + boff[nt] + kn);
    int a = kk >> 6;
    float hv = (float)hslT[a][rloc];
    bf16x8 tv = *(bf16x8*)&tsl[rloc][(kk & 32) + quad*8];
    bf16x8 af;
#pragma unroll
    for (int j = 0; j < 8; j++) af[j] = (__bf16)(hv * (float)tv[j]);
#pragma unroll
    for (int nt = 0; nt < 7; nt++)
      acc[nt] = __builtin_amdgcn_mfma_f32_16x16x32_bf16(af, bv[nt], acc[nt], 0, 0, 0);
#pragma unroll
    for (int nt = 0; nt < 7; nt++) bv[nt] = bn[nt];
  }

#pragma unroll
  for (int nt = 0; nt < 7; nt++)
#pragma unroll
    for (int reg = 0; reg < 4; reg++) {
      int n = m0 + wid*16 + quad*4 + reg;
      int l = nt*16 + col;
      if (n < NPAIR && l < NL)
        atomicAdd(&part[(long long)n*NL + l], acc[nt][reg]);
    }
}

// logits = part + b_bil; store in output dtype.
__global__ void k_final(const float* part, const void* b_bil, const int* flag,
                        void* out) {
  int i = blockIdx.x*256 + threadIdx.x;
  if (i >= NPAIR*NL) return;
  int l = i % NL;
  int f32 = *flag;
  float v = part[i] + ldin(b_bil, l, f32);
  if (f32) ((float*)out)[i] = v;
  else ((__hip_bfloat16*)out)[i] = __float2bfloat16(v);
}

extern "C" void kernel_launch(void* const* d_in, const int* in_sizes, int n_in,
                              void* d_out, int out_size, void* d_ws, size_t ws_size,
                              hipStream_t stream) {
  const void* seq    = d_in[0];
  const void* att    = d_in[1];
  const int*  etok   = (const int*)d_in[2];
  const void* emask  = d_in[3];
  const int*  hts    = (const int*)d_in[4];
  const void* wliner = d_in[5];
  const void* bliner = d_in[6];
  const void* wseg   = d_in[7];
  const void* bseg   = d_in[8];
  const void* whead  = d_in[9];
  const void* bhead  = d_in[10];
  const void* wtail  = d_in[11];
  const void* btail  = d_in[12];
  const void* wbil   = d_in[13];
  const void* bbil   = d_in[14];

  char* ws = (char*)d_ws;
  int*    flag  = (int*)ws;
  float*  e_emb = (float*)(ws + OFF_EEMB);
  float*  e_att = (float*)(ws + OFF_EATT);
  float*  sp    = (float*)(ws + OFF_SP);
  float*  h_t   = (float*)(ws + OFF_HT);
  __bf16* Xb    = (__bf16*)(ws + OFF_XB);
  __bf16* hsb   = (__bf16*)(ws + OFF_HSB);
  __bf16* tsb   = (__bf16*)(ws + OFF_TSB);
  float*  part  = (float*)(ws + OFF_PART);
  __bf16* whT   = (__bf16*)(ws + OFF_WHT);   // alias e_emb/e_att (after k_buildx)
  __bf16* wT    = (__bf16*)(ws + OFF_WT);    // alias h_t/Xb (after k_htmm)

  k_detect<<<1, 64, 0, stream>>>(whead, flag);
  k_eemb<<<BSZ*NEnt, 256, 0, stream>>>(seq, etok, emask, flag, e_emb);
  k_eatt<<<BSZ*NEnt*NH, 256, 0, stream>>>(att, etok, emask, flag, e_att);
  k_sp<<<BSZ*SEQ, 256, 0, stream>>>(seq, wliner, flag, sp);
  k_pair<<<NPAIR, 256, 0, stream>>>(e_att, sp, hts, bliner, wseg, bseg, flag, h_t);
  k_buildx<<<dim3(XROWS, 2), 256, 0, stream>>>(e_emb, h_t, hts, Xb);
  k_whT<<<dim3(16, 12, 2), 256, 0, stream>>>(whead, wtail, flag, whT);
  k_htmm<<<dim3(32, 6, 2), 256, 0, stream>>>(Xb, whT, bhead, btail, flag, hsb, tsb);
  k_wT<<<dim3(32, 12), 256, 0, stream>>>(wbil, flag, wT);
  k_zero<<<(NPAIR*NL/4 + 255)/256, 256, 0, stream>>>(part);
  k_bilmfma<<<dim3(32, 12), 256, 0, stream>>>(hsb, tsb, wT, part);
  k_final<<<(NPAIR*NL + 255)/256, 256, 0, stream>>>(part, bbil, flag, d_out);
}

// Round 4
// 590.672 us; speedup vs baseline: 2.5333x; 1.1419x over previous
//
#include <hip/hip_runtime.h>
#include <hip/hip_bf16.h>
#include <math.h>

#define BSZ 4
#define SEQ 1024
#define DIM 768
#define NH 12
#define NEnt 42
#define MM 8
#define PPairs 500
#define INC 3
#define OUTC 256
#define EMB 768
#define BLKsz 64
#define NG 12
#define NL 97
#define NPAIR (BSZ*PPairs)   // 2000
#define XROWS 2048           // padded rows for X / MFMA tiles

typedef __bf16 bf16x8 __attribute__((ext_vector_type(8)));
typedef __bf16 bf16x4 __attribute__((ext_vector_type(4)));
typedef float f32x4 __attribute__((ext_vector_type(4)));

// ---- workspace byte offsets (lifetime-aliased; peak ~26.2 MB) ----
// flag   @0        (4096)
// e_emb  @4096     516096   f32 [4*42*768]        dead after k_buildx
// e_att  @520192   4128768  bf16 [4*42*1024*12]   dead after k_pair ([be][s][h])
// sp     @8777728  49152    f32 [4096*3]          dead after k_pair
// h_t    @8826880  2048000  f32 [2000*256]        dead after k_buildx
// Xb     @10874880 8388608  bf16 [2*2048*1024]    dead after k_htmm
// hsb    @19263488 3072000  bf16 [2000*768]
// tsb    @22335488 3072000  bf16 [2000*768]
// part   @25407488 776000   f32 [2000*97]
// whT    @4096     3145728  bf16 [2*768*1024]     (alias e_emb/e_att; written after k_pair/buildx)
// wT     @8826880  9535488  bf16 [12*97*4096]     (alias h_t/Xb; written after k_htmm)
#define OFF_EEMB  4096
#define OFF_EATT  520192
#define OFF_SP    8777728
#define OFF_HT    8826880
#define OFF_XB    10874880
#define OFF_HSB   19263488
#define OFF_TSB   22335488
#define OFF_PART  25407488
#define OFF_WHT   4096
#define OFF_WT    8826880

// Load a float input that may be stored as f32 or bf16 (runtime flag).
__device__ __forceinline__ float ldin(const void* p, long long i, int f32) {
  if (f32) return ((const float*)p)[i];
  unsigned int u = (unsigned int)(((const unsigned short*)p)[i]) << 16;
  union { unsigned int u; float f; } c; c.u = u;
  return c.f;
}

__device__ __forceinline__ float tanhf_fast(float x) {
  float ax = fabsf(x);
  float t = __expf(-2.0f*ax);
  float r = (1.0f - t)/(1.0f + t);
  return x < 0.0f ? -r : r;
}

// Detect whether float inputs are f32 or bf16 (see R0 notes).
__global__ void k_detect(const void* w_head, int* flag) {
  int tid = threadIdx.x;  // 64
  unsigned int word = ((const unsigned int*)w_head)[tid];
  union { unsigned int u; float f; } c;
  c.u = (word & 0xFFFFu) << 16;
  float v = fabsf(c.f);
  unsigned long long m = __ballot(v > 1.0f);
  if (tid == 0) flag[0] = (__popcll(m) >= 8) ? 1 : 0;
}

// One-time: W_bil[(g*4096+k)*97+l] -> wT[(g*97+l)*4096+k] as bf16.
__global__ void k_wT(const void* wbil, const int* flag, __bf16* wT) {
  __shared__ float t[128][98];
  int kb = blockIdx.x, g = blockIdx.y, tid = threadIdx.x;  // 32 x 12, 256 thr
  int f32 = *flag;
  long long base = ((long long)g*4096 + kb*128)*97;
  for (int i = tid; i < 128*97; i += 256)
    t[i/97][i%97] = ldin(wbil, base + i, f32);
  __syncthreads();
  for (int j = tid; j < 97*128; j += 256) {
    int l = j >> 7, k = j & 127;
    wT[((long long)g*97 + l)*4096 + kb*128 + k] = (__bf16)t[k][l];
  }
}

// One-time: W_head/W_tail [1024][768] -> whT[y][768][1024] bf16.
__global__ void k_whT(const void* whead, const void* wtail, const int* flag,
                      __bf16* whT) {
  __shared__ float t[64][65];
  int kb = blockIdx.x, nb = blockIdx.y, y = blockIdx.z;  // 16 x 12 x 2
  int tid = threadIdx.x;  // 256
  int f32 = *flag;
  const void* W = y ? wtail : whead;
  for (int i = tid; i < 64*64; i += 256) {
    int r = i >> 6, c = i & 63;  // r = k-local, c = n-local
    t[r][c] = ldin(W, (long long)(kb*64 + r)*EMB + nb*64 + c, f32);
  }
  __syncthreads();
  for (int j = tid; j < 64*64; j += 256) {
    int r = j >> 6, k = j & 63;  // r = n-local, k = k-local
    whT[((long long)y*EMB + nb*64 + r)*1024 + kb*64 + k] = (__bf16)t[k][r];
  }
}

// e_emb[b,e,d] = logsumexp over valid mentions of seq_out[b, idx, d].
__global__ void k_eemb(const void* seq, const int* etok, const void* emask,
                       const int* flag, float* e_emb) {
  int be = blockIdx.x;
  int b = be / NEnt;
  int tid = threadIdx.x;          // 256
  int f32 = *flag;
  __shared__ int sidx[MM];
  __shared__ float sval[MM];
  if (tid < MM) {
    int t = etok[be*MM + tid];
    int ip = t + 1;
    float v = ldin(emask, be*MM + tid, f32);
    sval[tid] = (ip < SEQ) ? v : 0.0f;
    int ic = ip < 0 ? 0 : (ip > SEQ-1 ? SEQ-1 : ip);
    sidx[tid] = ic;
  }
  __syncthreads();
  float cnt = 0.0f;
#pragma unroll
  for (int m = 0; m < MM; m++) cnt += sval[m];
  for (int d = tid; d < DIM; d += 256) {
    float x[MM];
#pragma unroll
    for (int m = 0; m < MM; m++)
      x[m] = ldin(seq, ((long long)(b*SEQ) + sidx[m])*DIM + d, f32);
    float mx = -1e30f;
#pragma unroll
    for (int m = 0; m < MM; m++) if (sval[m] > 0.0f && x[m] > mx) mx = x[m];
    float s = 0.0f;
#pragma unroll
    for (int m = 0; m < MM; m++) if (sval[m] > 0.0f) s += expf(x[m] - mx);
    float e = (cnt > 0.0f) ? (mx + logf(s)) : 0.0f;
    e_emb[(long long)be*DIM + d] = e;
  }
}

// e_att[be][s][h] (bf16) = mean over valid mentions of attention[b,h,idx,s]
__global__ void k_eatt(const void* att, const int* etok, const void* emask,
                       const int* flag, __bf16* e_att) {
  int beh = blockIdx.x;
  int h = beh % NH;
  int be = beh / NH;
  int b = be / NEnt;
  int tid = threadIdx.x;           // 256
  int f32 = *flag;
  __shared__ int sidx[MM];
  __shared__ float sval[MM];
  if (tid < MM) {
    int t = etok[be*MM + tid];
    int ip = t + 1;
    float v = ldin(emask, be*MM + tid, f32);
    sval[tid] = (ip < SEQ) ? v : 0.0f;
    int ic = ip < 0 ? 0 : (ip > SEQ-1 ? SEQ-1 : ip);
    sidx[tid] = ic;
  }
  __syncthreads();
  float cnt = 0.0f;
#pragma unroll
  for (int m = 0; m < MM; m++) cnt += sval[m];
  float rs = (cnt > 0.0f) ? 1.0f/fmaxf(cnt, 1.0f) : 0.0f;
  long long abase = ((long long)(b*NH + h))*SEQ*SEQ;
  for (int s = tid; s < SEQ; s += 256) {
    float acc = 0.0f;
#pragma unroll
    for (int m = 0; m < MM; m++)
      if (sval[m] > 0.0f)
        acc += sval[m]*ldin(att, abase + (long long)sidx[m]*SEQ + s, f32);
    e_att[((long long)be*SEQ + s)*NH + h] = (__bf16)(acc*rs);
  }
}

// sp[b,s,c] = seq_out[b,s,:] @ W_liner[:,c]
__global__ void k_sp(const void* seq, const void* wliner, const int* flag,
                     float* sp) {
  int bs = blockIdx.x;
  int tid = threadIdx.x;          // 256
  int f32 = *flag;
  float a0 = 0, a1 = 0, a2 = 0;
  for (int d = tid; d < DIM; d += 256) {
    float x = ldin(seq, (long long)bs*DIM + d, f32);
    a0 += x*ldin(wliner, (long long)d*3 + 0, f32);
    a1 += x*ldin(wliner, (long long)d*3 + 1, f32);
    a2 += x*ldin(wliner, (long long)d*3 + 2, f32);
  }
  __shared__ float r0[256], r1[256], r2[256];
  r0[tid] = a0; r1[tid] = a1; r2[tid] = a2;
  __syncthreads();
  for (int o = 128; o > 0; o >>= 1) {
    if (tid < o) { r0[tid] += r0[tid+o]; r1[tid] += r1[tid+o]; r2[tid] += r2[tid+o]; }
    __syncthreads();
  }
  if (tid == 0) {
    sp[bs*3 + 0] = r0[0]; sp[bs*3 + 1] = r1[0]; sp[bs*3 + 2] = r2[0];
  }
}

// Per-pair weighted pooling + seg projection -> h_t[p][256]
__global__ void k_pair(const __bf16* e_att, const float* sp, const int* hts,
                       const void* bliner, const void* wseg, const void* bseg,
                       const int* flag, float* h_t) {
  int p = blockIdx.x;
  int b = p / PPairs;
  int tid = threadIdx.x;          // 256
  int f32 = *flag;
  int hi = hts[p*2 + 0];
  int ti = hts[p*2 + 1];
  const __bf16* ei = e_att + (long long)(b*NEnt + hi)*SEQ*NH;
  const __bf16* ej = e_att + (long long)(b*NEnt + ti)*SEQ*NH;
  float dn = 0, a0 = 0, a1 = 0, a2 = 0;
  for (int s = tid; s < SEQ; s += 256) {
    const __bf16* pi = ei + s*NH;
    const __bf16* pj = ej + s*NH;
    float q = 0.0f;
#pragma unroll
    for (int v = 0; v < 3; v++) {
      bf16x4 xi = *(const bf16x4*)(pi + v*4);
      bf16x4 xj = *(const bf16x4*)(pj + v*4);
#pragma unroll
      for (int h = 0; h < 4; h++) q += (float)xi[h]*(float)xj[h];
    }
    q *= (1.0f/NH);
    dn += q;
    a0 += q*sp[(b*SEQ + s)*3 + 0];
    a1 += q*sp[(b*SEQ + s)*3 + 1];
    a2 += q*sp[(b*SEQ + s)*3 + 2];
  }
  __shared__ float red[4][256];
  red[0][tid] = dn; red[1][tid] = a0; red[2][tid] = a1; red[3][tid] = a2;
  __syncthreads();
  for (int o = 128; o > 0; o >>= 1) {
    if (tid < o) {
      red[0][tid] += red[0][tid+o];
      red[1][tid] += red[1][tid+o];
      red[2][tid] += red[2][tid+o];
      red[3][tid] += red[3][tid+o];
    }
    __syncthreads();
  }
  float scale = 1.0f/(red[0][0] + 1e-5f);
  float v0 = red[1][0]*scale + ldin(bliner, 0, f32);
  float v1 = red[2][0]*scale + ldin(bliner, 1, f32);
  float v2 = red[3][0]*scale + ldin(bliner, 2, f32);
  float o = ldin(bseg, tid, f32)
          + v0*ldin(wseg, 0*OUTC + tid, f32)
          + v1*ldin(wseg, 1*OUTC + tid, f32)
          + v2*ldin(wseg, 2*OUTC + tid, f32);
  h_t[(long long)p*OUTC + tid] = o;
}

// Build X[y][p][k] = bf16(concat(e_emb[b, hts[p,y]], h_t[p])[k]); zero-pad rows.
__global__ void k_buildx(const float* e_emb, const float* h_t, const int* hts,
                         __bf16* Xb) {
  int p = blockIdx.x;              // 0..2047
  int y = blockIdx.y;
  int tid = threadIdx.x;           // 256
  __bf16* dst = Xb + ((long long)y*XROWS + p)*1024;
  if (p >= NPAIR) {
    for (int k = tid; k < 1024; k += 256) dst[k] = (__bf16)0.0f;
    return;
  }
  int b = p / PPairs;
  int ent = hts[p*2 + y];
  const float* er = e_emb + (long long)(b*NEnt + ent)*DIM;
  for (int k = tid; k < 1024; k += 256) {
    float v = (k < DIM) ? er[k] : h_t[(long long)p*OUTC + (k - DIM)];
    dst[k] = (__bf16)v;
  }
}

// MFMA head/tail projection: out = tanh(X @ W + b) as bf16 [2000][768].
// Depth-2 register prefetch; barrier-free (fragments straight from global).
__global__ __launch_bounds__(256, 2)
void k_htmm(const __bf16* Xb, const __bf16* whT,
            const void* bhead, const void* btail, const int* flag,
            __bf16* hsb, __bf16* tsb) {
  int tid = threadIdx.x;            // 256 = 4 waves
  int wid = tid >> 6, lane = tid & 63, quad = lane >> 4, col = lane & 15;
  int m0 = blockIdx.x*64 + wid*16;  // 32 m-blocks
  int n0 = blockIdx.y*128;          // 6 n-blocks
  int y  = blockIdx.z;
  int f32 = *flag;
  const __bf16* Xrow = Xb + ((long long)y*XROWS + m0 + col)*1024 + quad*8;
  const __bf16* wb   = whT + ((long long)y*EMB + n0 + col)*1024 + quad*8;
  f32x4 acc[8];
#pragma unroll
  for (int nt = 0; nt < 8; nt++) acc[nt] = (f32x4){0,0,0,0};

  bf16x8 avA = *(const bf16x8*)(Xrow + 0);
  bf16x8 avB = *(const bf16x8*)(Xrow + 32);
  bf16x8 bA[8], bB[8];
#pragma unroll
  for (int nt = 0; nt < 8; nt++) bA[nt] = *(const bf16x8*)(wb + nt*16*1024 + 0);
#pragma unroll
  for (int nt = 0; nt < 8; nt++) bB[nt] = *(const bf16x8*)(wb + nt*16*1024 + 32);

  for (int kk = 0; kk < 1024; kk += 64) {
    int kpA = (kk + 64 < 1024) ? kk + 64 : kk;
    int kpB = (kk + 96 < 1024) ? kk + 96 : kk + 32;
#pragma unroll
    for (int nt = 0; nt < 8; nt++)
      acc[nt] = __builtin_amdgcn_mfma_f32_16x16x32_bf16(avA, bA[nt], acc[nt], 0, 0, 0);
    avA = *(const bf16x8*)(Xrow + kpA);
#pragma unroll
    for (int nt = 0; nt < 8; nt++) bA[nt] = *(const bf16x8*)(wb + nt*16*1024 + kpA);
#pragma unroll
    for (int nt = 0; nt < 8; nt++)
      acc[nt] = __builtin_amdgcn_mfma_f32_16x16x32_bf16(avB, bB[nt], acc[nt], 0, 0, 0);
    avB = *(const bf16x8*)(Xrow + kpB);
#pragma unroll
    for (int nt = 0; nt < 8; nt++) bB[nt] = *(const bf16x8*)(wb + nt*16*1024 + kpB);
  }

  const void* Bv = y ? btail : bhead;
  __bf16* out = y ? tsb : hsb;
#pragma unroll
  for (int nt = 0; nt < 8; nt++) {
    int n = n0 + nt*16 + col;
    float bias = ldin(Bv, n, f32);
#pragma unroll
    for (int reg = 0; reg < 4; reg++) {
      int m = m0 + quad*4 + reg;
      if (m < NPAIR)
        out[(long long)m*EMB + n] = (__bf16)tanhf_fast(acc[nt][reg] + bias);
    }
  }
}

// Zero part (re-poisoned to 0xAA each call).
__global__ void k_zero(float* part) {
  int i = blockIdx.x*256 + threadIdx.x;     // float4 index
  if (i < (NPAIR*NL)/4) ((f32x4*)part)[i] = (f32x4){0,0,0,0};
}

// MFMA bilinear: part[n][l] += sum_{a,b} hs[n,g,a]*ts[n,g,b]*W_bil[(g,a,b),l]
// Grid (32 m, 12 g, 2 kq) = 768 blocks = 3/CU. Depth-2 register B prefetch.
__global__ __launch_bounds__(256, 2)
void k_bilmfma(const __bf16* hsb, const __bf16* tsb,
               const __bf16* wT, float* part) {
  __shared__ __bf16 hslT[32][72];   // [a_local][row], conflict-free scalar read
  __shared__ __bf16 tsl[64][72];    // [row][b]
  int tid = threadIdx.x;            // 256 = 4 waves
  int m0 = blockIdx.x * 64;         // 32 m-blocks
  int g  = blockIdx.y;              // 0..11
  int kq = blockIdx.z;              // 0..1 (k-halves; a in [kq*32, kq*32+32))
  int wid = tid >> 6, lane = tid & 63, quad = lane >> 4, col = lane & 15;

  // stage hslT: 64 rows x 32 a-vals (one round)
  {
    int r = tid >> 2, c0 = (tid & 3)*8;
    int gr = m0 + r;
    bf16x8 hv = {};
    if (gr < NPAIR)
      hv = *(const bf16x8*)(hsb + (long long)gr*EMB + g*BLKsz + kq*32 + c0);
#pragma unroll
    for (int j = 0; j < 8; j++) hslT[c0 + j][r] = hv[j];
  }
  // stage tsl: 64 rows x 64 (two rounds)
  for (int i = tid; i < 64*8; i += 256) {
    int r = i >> 3, c0 = (i & 7)*8;
    int gr = m0 + r;
    bf16x8 tv = {};
    if (gr < NPAIR)
      tv = *(const bf16x8*)(tsb + (long long)gr*EMB + g*BLKsz + c0);
    *(bf16x8*)&tsl[r][c0] = tv;
  }
  __syncthreads();

  int rloc = wid*16 + col;
  const __bf16* wg = wT + (long long)g*NL*4096 + kq*2048 + quad*8;
  int boff[7];
#pragma unroll
  for (int nt = 0; nt < 7; nt++) {
    int l = nt*16 + col; if (l > 96) l = 96;
    boff[nt] = l*4096;
  }
  f32x4 acc[7];
#pragma unroll
  for (int nt = 0; nt < 7; nt++) acc[nt] = (f32x4){0,0,0,0};

  bf16x8 bufA[7], bufB[7];
#pragma unroll
  for (int nt = 0; nt < 7; nt++) bufA[nt] = *(const bf16x8*)(wg + boff[nt] + 0);
#pragma unroll
  for (int nt = 0; nt < 7; nt++) bufB[nt] = *(const bf16x8*)(wg + boff[nt] + 32);

  for (int i2 = 0; i2 < 32; i2++) {
    int k0 = i2*64;
    int kpA = (k0 + 64 < 2048) ? k0 + 64 : k0;
    int kpB = (k0 + 96 < 2048) ? k0 + 96 : k0 + 32;
    float hv = (float)hslT[i2][rloc];
    // step A: b-range [0,32)
    {
      bf16x8 tv = *(bf16x8*)&tsl[rloc][quad*8];
      bf16x8 af;
#pragma unroll
      for (int j = 0; j < 8; j++) af[j] = (__bf16)(hv * (float)tv[j]);
#pragma unroll
      for (int nt = 0; nt < 7; nt++)
        acc[nt] = __builtin_amdgcn_mfma_f32_16x16x32_bf16(af, bufA[nt], acc[nt], 0, 0, 0);
#pragma unroll
      for (int nt = 0; nt < 7; nt++)
        bufA[nt] = *(const bf16x8*)(wg + boff[nt] + kpA);
    }
    // step B: b-range [32,64)
    {
      bf16x8 tv = *(bf16x8*)&tsl[rloc][32 + quad*8];
      bf16x8 af;
#pragma unroll
      for (int j = 0; j < 8; j++) af[j] = (__bf16)(hv * (float)tv[j]);
#pragma unroll
      for (int nt = 0; nt < 7; nt++)
        acc[nt] = __builtin_amdgcn_mfma_f32_16x16x32_bf16(af, bufB[nt], acc[nt], 0, 0, 0);
#pragma unroll
      for (int nt = 0; nt < 7; nt++)
        bufB[nt] = *(const bf16x8*)(wg + boff[nt] + kpB);
    }
  }

#pragma unroll
  for (int nt = 0; nt < 7; nt++)
#pragma unroll
    for (int reg = 0; reg < 4; reg++) {
      int n = m0 + wid*16 + quad*4 + reg;
      int l = nt*16 + col;
      if (n < NPAIR && l < NL)
        atomicAdd(&part[(long long)n*NL + l], acc[nt][reg]);
    }
}

// logits = part + b_bil; store in output dtype.
__global__ void k_final(const float* part, const void* b_bil, const int* flag,
                        void* out) {
  int i = blockIdx.x*256 + threadIdx.x;
  if (i >= NPAIR*NL) return;
  int l = i % NL;
  int f32 = *flag;
  float v = part[i] + ldin(b_bil, l, f32);
  if (f32) ((float*)out)[i] = v;
  else ((__hip_bfloat16*)out)[i] = __float2bfloat16(v);
}

extern "C" void kernel_launch(void* const* d_in, const int* in_sizes, int n_in,
                              void* d_out, int out_size, void* d_ws, size_t ws_size,
                              hipStream_t stream) {
  const void* seq    = d_in[0];
  const void* att    = d_in[1];
  const int*  etok   = (const int*)d_in[2];
  const void* emask  = d_in[3];
  const int*  hts    = (const int*)d_in[4];
  const void* wliner = d_in[5];
  const void* bliner = d_in[6];
  const void* wseg   = d_in[7];
  const void* bseg   = d_in[8];
  const void* whead  = d_in[9];
  const void* bhead  = d_in[10];
  const void* wtail  = d_in[11];
  const void* btail  = d_in[12];
  const void* wbil   = d_in[13];
  const void* bbil   = d_in[14];

  char* ws = (char*)d_ws;
  int*    flag  = (int*)ws;
  float*  e_emb = (float*)(ws + OFF_EEMB);
  __bf16* e_att = (__bf16*)(ws + OFF_EATT);
  float*  sp    = (float*)(ws + OFF_SP);
  float*  h_t   = (float*)(ws + OFF_HT);
  __bf16* Xb    = (__bf16*)(ws + OFF_XB);
  __bf16* hsb   = (__bf16*)(ws + OFF_HSB);
  __bf16* tsb   = (__bf16*)(ws + OFF_TSB);
  float*  part  = (float*)(ws + OFF_PART);
  __bf16* whT   = (__bf16*)(ws + OFF_WHT);   // alias e_emb/e_att (after k_pair/k_buildx)
  __bf16* wT    = (__bf16*)(ws + OFF_WT);    // alias h_t/Xb (after k_htmm)

  k_detect<<<1, 64, 0, stream>>>(whead, flag);
  k_eemb<<<BSZ*NEnt, 256, 0, stream>>>(seq, etok, emask, flag, e_emb);
  k_eatt<<<BSZ*NEnt*NH, 256, 0, stream>>>(att, etok, emask, flag, e_att);
  k_sp<<<BSZ*SEQ, 256, 0, stream>>>(seq, wliner, flag, sp);
  k_pair<<<NPAIR, 256, 0, stream>>>(e_att, sp, hts, bliner, wseg, bseg, flag, h_t);
  k_buildx<<<dim3(XROWS, 2), 256, 0, stream>>>(e_emb, h_t, hts, Xb);
  k_whT<<<dim3(16, 12, 2), 256, 0, stream>>>(whead, wtail, flag, whT);
  k_htmm<<<dim3(32, 6, 2), 256, 0, stream>>>(Xb, whT, bhead, btail, flag, hsb, tsb);
  k_wT<<<dim3(32, 12), 256, 0, stream>>>(wbil, flag, wT);
  k_zero<<<(NPAIR*NL/4 + 255)/256, 256, 0, stream>>>(part);
  k_bilmfma<<<dim3(32, 12, 2), 256, 0, stream>>>(hsb, tsb, wT, part);
  k_final<<<(NPAIR*NL + 255)/256, 256, 0, stream>>>(part, bbil, flag, d_out);
}

// Round 5
// 452.528 us; speedup vs baseline: 3.3067x; 1.3053x over previous
//
#include <hip/hip_runtime.h>
#include <hip/hip_bf16.h>
#include <math.h>

#define BSZ 4
#define SEQ 1024
#define DIM 768
#define NH 12
#define NEnt 42
#define MM 8
#define PPairs 500
#define INC 3
#define OUTC 256
#define EMB 768
#define BLKsz 64
#define NG 12
#define NL 97
#define NPAIR (BSZ*PPairs)   // 2000
#define XROWS 2048           // padded rows for X / MFMA tiles
#define NCHUNK 24            // bilinear (g, k-half) chunks

typedef __bf16 bf16x8 __attribute__((ext_vector_type(8)));
typedef __bf16 bf16x4 __attribute__((ext_vector_type(4)));
typedef float f32x4 __attribute__((ext_vector_type(4)));

// ---- workspace byte offsets (lifetime-aliased; peak ~29.2 MiB) ----
// flag   @0
// e_emb  @4096      516096   f32  dead after k_buildx
// e_att  @520192    4128768  bf16 [be][s][h], dead after k_pair
// sp     @4648960   49152    f32  dead after k_pair
// h_t    @4698112   2048000  f32  dead after k_buildx
// Xb     @6746112   8388608  bf16 [2][2048][1024], dead after k_htmm
// hsb    @15134720  3072000  bf16 [2000][768]
// tsb    @18206720  3072000  bf16 [2000][768]
// part24 @21278720  9312000  f16  [24][2000][97]
// whT    @520192    3145728  bf16 (alias e_att; written after k_pair)
// wT     @4698112   9535488  bf16 (alias h_t+Xb; written after k_htmm)
#define OFF_EEMB  4096
#define OFF_EATT  520192
#define OFF_SP    4648960
#define OFF_HT    4698112
#define OFF_XB    6746112
#define OFF_HSB   15134720
#define OFF_TSB   18206720
#define OFF_PART  21278720
#define OFF_WHT   520192
#define OFF_WT    4698112

// Load a float input that may be stored as f32 or bf16 (runtime flag).
__device__ __forceinline__ float ldin(const void* p, long long i, int f32) {
  if (f32) return ((const float*)p)[i];
  unsigned int u = (unsigned int)(((const unsigned short*)p)[i]) << 16;
  union { unsigned int u; float f; } c; c.u = u;
  return c.f;
}

__device__ __forceinline__ float tanhf_fast(float x) {
  float ax = fabsf(x);
  float t = __expf(-2.0f*ax);
  float r = (1.0f - t)/(1.0f + t);
  return x < 0.0f ? -r : r;
}

// Detect whether float inputs are f32 or bf16 (see R0 notes).
__global__ void k_detect(const void* w_head, int* flag) {
  int tid = threadIdx.x;  // 64
  unsigned int word = ((const unsigned int*)w_head)[tid];
  union { unsigned int u; float f; } c;
  c.u = (word & 0xFFFFu) << 16;
  float v = fabsf(c.f);
  unsigned long long m = __ballot(v > 1.0f);
  if (tid == 0) flag[0] = (__popcll(m) >= 8) ? 1 : 0;
}

// One-time: W_bil[(g*4096+k)*97+l] -> wT[(g*97+l)*4096+k] as bf16.
__global__ void k_wT(const void* wbil, const int* flag, __bf16* wT) {
  __shared__ float t[128][98];
  int kb = blockIdx.x, g = blockIdx.y, tid = threadIdx.x;  // 32 x 12, 256 thr
  int f32 = *flag;
  long long base = ((long long)g*4096 + kb*128)*97;
  for (int i = tid; i < 128*97; i += 256)
    t[i/97][i%97] = ldin(wbil, base + i, f32);
  __syncthreads();
  for (int j = tid; j < 97*128; j += 256) {
    int l = j >> 7, k = j & 127;
    wT[((long long)g*97 + l)*4096 + kb*128 + k] = (__bf16)t[k][l];
  }
}

// One-time: W_head/W_tail [1024][768] -> whT[y][768][1024] bf16.
__global__ void k_whT(const void* whead, const void* wtail, const int* flag,
                      __bf16* whT) {
  __shared__ float t[64][65];
  int kb = blockIdx.x, nb = blockIdx.y, y = blockIdx.z;  // 16 x 12 x 2
  int tid = threadIdx.x;  // 256
  int f32 = *flag;
  const void* W = y ? wtail : whead;
  for (int i = tid; i < 64*64; i += 256) {
    int r = i >> 6, c = i & 63;  // r = k-local, c = n-local
    t[r][c] = ldin(W, (long long)(kb*64 + r)*EMB + nb*64 + c, f32);
  }
  __syncthreads();
  for (int j = tid; j < 64*64; j += 256) {
    int r = j >> 6, k = j & 63;  // r = n-local, k = k-local
    whT[((long long)y*EMB + nb*64 + r)*1024 + kb*64 + k] = (__bf16)t[k][r];
  }
}

// e_emb[b,e,d] = logsumexp over valid mentions of seq_out[b, idx, d].
__global__ void k_eemb(const void* seq, const int* etok, const void* emask,
                       const int* flag, float* e_emb) {
  int be = blockIdx.x;
  int b = be / NEnt;
  int tid = threadIdx.x;          // 256
  int f32 = *flag;
  __shared__ int sidx[MM];
  __shared__ float sval[MM];
  if (tid < MM) {
    int t = etok[be*MM + tid];
    int ip = t + 1;
    float v = ldin(emask, be*MM + tid, f32);
    sval[tid] = (ip < SEQ) ? v : 0.0f;
    int ic = ip < 0 ? 0 : (ip > SEQ-1 ? SEQ-1 : ip);
    sidx[tid] = ic;
  }
  __syncthreads();
  float cnt = 0.0f;
#pragma unroll
  for (int m = 0; m < MM; m++) cnt += sval[m];
  for (int d = tid; d < DIM; d += 256) {
    float x[MM];
#pragma unroll
    for (int m = 0; m < MM; m++)
      x[m] = ldin(seq, ((long long)(b*SEQ) + sidx[m])*DIM + d, f32);
    float mx = -1e30f;
#pragma unroll
    for (int m = 0; m < MM; m++) if (sval[m] > 0.0f && x[m] > mx) mx = x[m];
    float s = 0.0f;
#pragma unroll
    for (int m = 0; m < MM; m++) if (sval[m] > 0.0f) s += expf(x[m] - mx);
    float e = (cnt > 0.0f) ? (mx + logf(s)) : 0.0f;
    e_emb[(long long)be*DIM + d] = e;
  }
}

// e_att[be][s][h] (bf16) = mean over valid mentions of attention[b,h,idx,s]
__global__ void k_eatt(const void* att, const int* etok, const void* emask,
                       const int* flag, __bf16* e_att) {
  int beh = blockIdx.x;
  int h = beh % NH;
  int be = beh / NH;
  int b = be / NEnt;
  int tid = threadIdx.x;           // 256
  int f32 = *flag;
  __shared__ int sidx[MM];
  __shared__ float sval[MM];
  if (tid < MM) {
    int t = etok[be*MM + tid];
    int ip = t + 1;
    float v = ldin(emask, be*MM + tid, f32);
    sval[tid] = (ip < SEQ) ? v : 0.0f;
    int ic = ip < 0 ? 0 : (ip > SEQ-1 ? SEQ-1 : ip);
    sidx[tid] = ic;
  }
  __syncthreads();
  float cnt = 0.0f;
#pragma unroll
  for (int m = 0; m < MM; m++) cnt += sval[m];
  float rs = (cnt > 0.0f) ? 1.0f/fmaxf(cnt, 1.0f) : 0.0f;
  long long abase = ((long long)(b*NH + h))*SEQ*SEQ;
  for (int s = tid; s < SEQ; s += 256) {
    float acc = 0.0f;
#pragma unroll
    for (int m = 0; m < MM; m++)
      if (sval[m] > 0.0f)
        acc += sval[m]*ldin(att, abase + (long long)sidx[m]*SEQ + s, f32);
    e_att[((long long)be*SEQ + s)*NH + h] = (__bf16)(acc*rs);
  }
}

// sp[b,s,c] = seq_out[b,s,:] @ W_liner[:,c]
__global__ void k_sp(const void* seq, const void* wliner, const int* flag,
                     float* sp) {
  int bs = blockIdx.x;
  int tid = threadIdx.x;          // 256
  int f32 = *flag;
  float a0 = 0, a1 = 0, a2 = 0;
  for (int d = tid; d < DIM; d += 256) {
    float x = ldin(seq, (long long)bs*DIM + d, f32);
    a0 += x*ldin(wliner, (long long)d*3 + 0, f32);
    a1 += x*ldin(wliner, (long long)d*3 + 1, f32);
    a2 += x*ldin(wliner, (long long)d*3 + 2, f32);
  }
  __shared__ float r0[256], r1[256], r2[256];
  r0[tid] = a0; r1[tid] = a1; r2[tid] = a2;
  __syncthreads();
  for (int o = 128; o > 0; o >>= 1) {
    if (tid < o) { r0[tid] += r0[tid+o]; r1[tid] += r1[tid+o]; r2[tid] += r2[tid+o]; }
    __syncthreads();
  }
  if (tid == 0) {
    sp[bs*3 + 0] = r0[0]; sp[bs*3 + 1] = r1[0]; sp[bs*3 + 2] = r2[0];
  }
}

// Per-pair weighted pooling + seg projection -> h_t[p][256]
__global__ void k_pair(const __bf16* e_att, const float* sp, const int* hts,
                       const void* bliner, const void* wseg, const void* bseg,
                       const int* flag, float* h_t) {
  int p = blockIdx.x;
  int b = p / PPairs;
  int tid = threadIdx.x;          // 256
  int f32 = *flag;
  int hi = hts[p*2 + 0];
  int ti = hts[p*2 + 1];
  const __bf16* ei = e_att + (long long)(b*NEnt + hi)*SEQ*NH;
  const __bf16* ej = e_att + (long long)(b*NEnt + ti)*SEQ*NH;
  float dn = 0, a0 = 0, a1 = 0, a2 = 0;
  for (int s = tid; s < SEQ; s += 256) {
    const __bf16* pi = ei + s*NH;
    const __bf16* pj = ej + s*NH;
    float q = 0.0f;
#pragma unroll
    for (int v = 0; v < 3; v++) {
      bf16x4 xi = *(const bf16x4*)(pi + v*4);
      bf16x4 xj = *(const bf16x4*)(pj + v*4);
#pragma unroll
      for (int h = 0; h < 4; h++) q += (float)xi[h]*(float)xj[h];
    }
    q *= (1.0f/NH);
    dn += q;
    a0 += q*sp[(b*SEQ + s)*3 + 0];
    a1 += q*sp[(b*SEQ + s)*3 + 1];
    a2 += q*sp[(b*SEQ + s)*3 + 2];
  }
  __shared__ float red[4][256];
  red[0][tid] = dn; red[1][tid] = a0; red[2][tid] = a1; red[3][tid] = a2;
  __syncthreads();
  for (int o = 128; o > 0; o >>= 1) {
    if (tid < o) {
      red[0][tid] += red[0][tid+o];
      red[1][tid] += red[1][tid+o];
      red[2][tid] += red[2][tid+o];
      red[3][tid] += red[3][tid+o];
    }
    __syncthreads();
  }
  float scale = 1.0f/(red[0][0] + 1e-5f);
  float v0 = red[1][0]*scale + ldin(bliner, 0, f32);
  float v1 = red[2][0]*scale + ldin(bliner, 1, f32);
  float v2 = red[3][0]*scale + ldin(bliner, 2, f32);
  float o = ldin(bseg, tid, f32)
          + v0*ldin(wseg, 0*OUTC + tid, f32)
          + v1*ldin(wseg, 1*OUTC + tid, f32)
          + v2*ldin(wseg, 2*OUTC + tid, f32);
  h_t[(long long)p*OUTC + tid] = o;
}

// Build X[y][p][k] = bf16(concat(e_emb[b, hts[p,y]], h_t[p])[k]); zero-pad rows.
__global__ void k_buildx(const float* e_emb, const float* h_t, const int* hts,
                         __bf16* Xb) {
  int p = blockIdx.x;              // 0..2047
  int y = blockIdx.y;
  int tid = threadIdx.x;           // 256
  __bf16* dst = Xb + ((long long)y*XROWS + p)*1024;
  if (p >= NPAIR) {
    for (int k = tid; k < 1024; k += 256) dst[k] = (__bf16)0.0f;
    return;
  }
  int b = p / PPairs;
  int ent = hts[p*2 + y];
  const float* er = e_emb + (long long)(b*NEnt + ent)*DIM;
  for (int k = tid; k < 1024; k += 256) {
    float v = (k < DIM) ? er[k] : h_t[(long long)p*OUTC + (k - DIM)];
    dst[k] = (__bf16)v;
  }
}

// MFMA head/tail: out = tanh(X @ W + b) bf16 [2000][768].
// Block = 128 thr = 2 waves; wave = 64 rows (4 mf) x 64 cols (4 nt).
// A and B double-buffered through LDS (k-chunks of 64).
__global__ __launch_bounds__(128, 2)
void k_htmm(const __bf16* Xb, const __bf16* whT,
            const void* bhead, const void* btail, const int* flag,
            __bf16* hsb, __bf16* tsb) {
  __shared__ __bf16 Xa[2][128][72];
  __shared__ __bf16 Bb[2][64][72];
  int tid = threadIdx.x;            // 128
  int w = tid >> 6, lane = tid & 63, quad = lane >> 4, col = lane & 15;
  int m0 = blockIdx.x*128;          // 16 m-blocks
  int n0 = blockIdx.y*64;           // 12 n-blocks
  int y  = blockIdx.z;
  int f32 = *flag;
  const __bf16* Xg = Xb + (long long)y*XROWS*1024;
  const __bf16* Wg = whT + ((long long)y*EMB + n0)*1024;

  // stage chunk kk into buffer p
  auto stage = [&](int kk, int p) {
#pragma unroll
    for (int it = 0; it < 8; it++) {
      int r = (tid >> 3) + 16*it;
      int c0 = (tid & 7)*8;
      bf16x8 v = *(const bf16x8*)(Xg + (long long)(m0 + r)*1024 + kk + c0);
      *(bf16x8*)&Xa[p][r][c0] = v;
    }
#pragma unroll
    for (int it = 0; it < 4; it++) {
      int r = tid >> 1;
      int c0 = (tid & 1)*32 + it*8;
      bf16x8 v = *(const bf16x8*)(Wg + (long long)r*1024 + kk + c0);
      *(bf16x8*)&Bb[p][r][c0] = v;
    }
  };

  f32x4 acc[4][4];
#pragma unroll
  for (int mf = 0; mf < 4; mf++)
#pragma unroll
    for (int nt = 0; nt < 4; nt++) acc[mf][nt] = (f32x4){0,0,0,0};

  stage(0, 0);
  __syncthreads();
  for (int c = 0; c < 16; c++) {
    int p = c & 1;
    if (c + 1 < 16) stage((c+1)*64, p ^ 1);
#pragma unroll
    for (int s = 0; s < 2; s++) {
      bf16x8 av[4], bv[4];
#pragma unroll
      for (int mf = 0; mf < 4; mf++)
        av[mf] = *(bf16x8*)&Xa[p][w*64 + mf*16 + col][s*32 + quad*8];
#pragma unroll
      for (int nt = 0; nt < 4; nt++)
        bv[nt] = *(bf16x8*)&Bb[p][nt*16 + col][s*32 + quad*8];
#pragma unroll
      for (int mf = 0; mf < 4; mf++)
#pragma unroll
        for (int nt = 0; nt < 4; nt++)
          acc[mf][nt] = __builtin_amdgcn_mfma_f32_16x16x32_bf16(av[mf], bv[nt],
                                                                acc[mf][nt], 0, 0, 0);
    }
    __syncthreads();
  }

  const void* Bv = y ? btail : bhead;
  __bf16* out = y ? tsb : hsb;
#pragma unroll
  for (int nt = 0; nt < 4; nt++) {
    int n = n0 + nt*16 + col;
    float bias = ldin(Bv, n, f32);
#pragma unroll
    for (int mf = 0; mf < 4; mf++)
#pragma unroll
      for (int reg = 0; reg < 4; reg++) {
        int m = m0 + w*64 + mf*16 + quad*4 + reg;
        if (m < NPAIR)
          out[(long long)m*EMB + n] = (__bf16)tanhf_fast(acc[mf][nt][reg] + bias);
      }
  }
}

// MFMA bilinear: part24[c][n][l] = sum over chunk c=(g,kh) of
//   hs[n,g,a]*ts[n,g,b]*W_bil[(g,a,b),l].
// Block = 128 thr = 2 waves; wave = 64 rows (4 mf) x 112 cols (7 nt).
// ts slices live in registers (loop-invariant); hs via LDS transpose;
// B depth-2 register prefetch; NO barriers in K-loop.
__global__ __launch_bounds__(128, 2)
void k_bilmfma(const __bf16* hsb, const __bf16* tsb,
               const __bf16* wT, _Float16* part24) {
  __shared__ __bf16 hslT[32][136];  // [a_local][row]
  int tid = threadIdx.x;            // 128
  int w = tid >> 6, lane = tid & 63, quad = lane >> 4, col = lane & 15;
  int m0 = blockIdx.x*128;          // 16 m-blocks
  int c  = blockIdx.y;              // 0..23
  int g  = c >> 1, kh = c & 1;

  // stage hslT: 128 rows x 32 a-values (transposed)
  {
    int row = m0 + tid; if (row > NPAIR-1) row = NPAIR-1;
    const __bf16* hp = hsb + (long long)row*EMB + g*BLKsz + kh*32;
#pragma unroll
    for (int c0 = 0; c0 < 4; c0++) {
      bf16x8 hv = *(const bf16x8*)(hp + c0*8);
#pragma unroll
      for (int j = 0; j < 8; j++) hslT[c0*8 + j][tid] = hv[j];
    }
  }
  // ts register slices: tsv[mf][half] = ts[row(mf)][g*64 + half*32 + quad*8 ..+8]
  bf16x8 tsv[4][2];
#pragma unroll
  for (int mf = 0; mf < 4; mf++) {
    int row = m0 + w*64 + mf*16 + col; if (row > NPAIR-1) row = NPAIR-1;
    const __bf16* tp = tsb + (long long)row*EMB + g*BLKsz + quad*8;
    tsv[mf][0] = *(const bf16x8*)(tp);
    tsv[mf][1] = *(const bf16x8*)(tp + 32);
  }
  __syncthreads();

  const __bf16* wg = wT + (long long)g*NL*4096 + kh*2048 + quad*8;
  int boff[7];
#pragma unroll
  for (int nt = 0; nt < 7; nt++) {
    int l = nt*16 + col; if (l > 96) l = 96;
    boff[nt] = l*4096;
  }
  f32x4 acc[4][7];
#pragma unroll
  for (int mf = 0; mf < 4; mf++)
#pragma unroll
    for (int nt = 0; nt < 7; nt++) acc[mf][nt] = (f32x4){0,0,0,0};

  bf16x8 bv[2][7];
#pragma unroll
  for (int nt = 0; nt < 7; nt++) bv[0][nt] = *(const bf16x8*)(wg + boff[nt]);
#pragma unroll
  for (int nt = 0; nt < 7; nt++) bv[1][nt] = *(const bf16x8*)(wg + boff[nt] + 32);

  for (int a = 0; a < 32; a++) {
    float hv[4];
#pragma unroll
    for (int mf = 0; mf < 4; mf++)
      hv[mf] = (float)hslT[a][w*64 + mf*16 + col];
#pragma unroll
    for (int half = 0; half < 2; half++) {
      bf16x8 af[4];
#pragma unroll
      for (int mf = 0; mf < 4; mf++)
#pragma unroll
        for (int j = 0; j < 8; j++)
          af[mf][j] = (__bf16)(hv[mf] * (float)tsv[mf][half][j]);
#pragma unroll
      for (int mf = 0; mf < 4; mf++)
#pragma unroll
        for (int nt = 0; nt < 7; nt++)
          acc[mf][nt] = __builtin_amdgcn_mfma_f32_16x16x32_bf16(af[mf], bv[half][nt],
                                                                acc[mf][nt], 0, 0, 0);
      int knext = (a+1)*64 + half*32;
      if (knext >= 2048) knext = a*64 + half*32;  // harmless refill at tail
#pragma unroll
      for (int nt = 0; nt < 7; nt++)
        bv[half][nt] = *(const bf16x8*)(wg + boff[nt] + knext);
    }
  }

  _Float16* ps = part24 + (long long)c*NPAIR*NL;
#pragma unroll
  for (int mf = 0; mf < 4; mf++)
#pragma unroll
    for (int nt = 0; nt < 7; nt++)
#pragma unroll
      for (int reg = 0; reg < 4; reg++) {
        int n = m0 + w*64 + mf*16 + quad*4 + reg;
        int l = nt*16 + col;
        if (n < NPAIR && l < NL)
          ps[(long long)n*NL + l] = (_Float16)acc[mf][nt][reg];
      }
}

// logits = sum_c part24 + b_bil; store in output dtype.
__global__ void k_final(const _Float16* part24, const void* b_bil, const int* flag,
                        void* out) {
  int i = blockIdx.x*256 + threadIdx.x;
  if (i >= NPAIR*NL) return;
  int l = i % NL;
  int f32 = *flag;
  float v = ldin(b_bil, l, f32);
#pragma unroll
  for (int c = 0; c < NCHUNK; c++) v += (float)part24[(long long)c*NPAIR*NL + i];
  if (f32) ((float*)out)[i] = v;
  else ((__hip_bfloat16*)out)[i] = __float2bfloat16(v);
}

extern "C" void kernel_launch(void* const* d_in, const int* in_sizes, int n_in,
                              void* d_out, int out_size, void* d_ws, size_t ws_size,
                              hipStream_t stream) {
  const void* seq    = d_in[0];
  const void* att    = d_in[1];
  const int*  etok   = (const int*)d_in[2];
  const void* emask  = d_in[3];
  const int*  hts    = (const int*)d_in[4];
  const void* wliner = d_in[5];
  const void* bliner = d_in[6];
  const void* wseg   = d_in[7];
  const void* bseg   = d_in[8];
  const void* whead  = d_in[9];
  const void* bhead  = d_in[10];
  const void* wtail  = d_in[11];
  const void* btail  = d_in[12];
  const void* wbil   = d_in[13];
  const void* bbil   = d_in[14];

  char* ws = (char*)d_ws;
  int*      flag   = (int*)ws;
  float*    e_emb  = (float*)(ws + OFF_EEMB);
  __bf16*   e_att  = (__bf16*)(ws + OFF_EATT);
  float*    sp     = (float*)(ws + OFF_SP);
  float*    h_t    = (float*)(ws + OFF_HT);
  __bf16*   Xb     = (__bf16*)(ws + OFF_XB);
  __bf16*   hsb    = (__bf16*)(ws + OFF_HSB);
  __bf16*   tsb    = (__bf16*)(ws + OFF_TSB);
  _Float16* part24 = (_Float16*)(ws + OFF_PART);
  __bf16*   whT    = (__bf16*)(ws + OFF_WHT);   // alias e_att (after k_pair)
  __bf16*   wT     = (__bf16*)(ws + OFF_WT);    // alias h_t+Xb (after k_htmm)

  k_detect<<<1, 64, 0, stream>>>(whead, flag);
  k_eemb<<<BSZ*NEnt, 256, 0, stream>>>(seq, etok, emask, flag, e_emb);
  k_eatt<<<BSZ*NEnt*NH, 256, 0, stream>>>(att, etok, emask, flag, e_att);
  k_sp<<<BSZ*SEQ, 256, 0, stream>>>(seq, wliner, flag, sp);
  k_pair<<<NPAIR, 256, 0, stream>>>(e_att, sp, hts, bliner, wseg, bseg, flag, h_t);
  k_buildx<<<dim3(XROWS, 2), 256, 0, stream>>>(e_emb, h_t, hts, Xb);
  k_whT<<<dim3(16, 12, 2), 256, 0, stream>>>(whead, wtail, flag, whT);
  k_htmm<<<dim3(16, 12, 2), 128, 0, stream>>>(Xb, whT, bhead, btail, flag, hsb, tsb);
  k_wT<<<dim3(32, 12), 256, 0, stream>>>(wbil, flag, wT);
  k_bilmfma<<<dim3(16, NCHUNK), 128, 0, stream>>>(hsb, tsb, wT, part24);
  k_final<<<(NPAIR*NL + 255)/256, 256, 0, stream>>>(part24, bbil, flag, d_out);
}